// Round 13
// baseline (303.633 us; speedup 1.0000x reference)
//
#include <hip/hip_runtime.h>
#include <hip/hip_bf16.h>

typedef __attribute__((ext_vector_type(8))) short bf16x8;
typedef __attribute__((ext_vector_type(4))) float f32x4;
typedef __attribute__((ext_vector_type(2))) long lx2;

__device__ __forceinline__ uint pack_bf16x2(float a, float b) {
    __hip_bfloat162 p = __float22bfloat162_rn(make_float2(a, b));
    union { __hip_bfloat162 h; uint u; } c; c.h = p; return c.u;
}

__device__ __forceinline__ float fast_tanh(float x) {
    float e = __expf(2.f * x);
    return 1.f - 2.f * __builtin_amdgcn_rcpf(e + 1.f);
}

__device__ __forceinline__ float wredmax(float v) {
    #pragma unroll
    for (int o = 32; o; o >>= 1) v = fmaxf(v, __shfl_xor(v, o, 64));
    return v;
}
__device__ __forceinline__ float wredsum(float v) {
    #pragma unroll
    for (int o = 32; o; o >>= 1) v += __shfl_xor(v, o, 64);
    return v;
}

__device__ __forceinline__ void gload16(const void* g, void* l) {
    __builtin_amdgcn_global_load_lds(
        (const __attribute__((address_space(1))) void*)g,
        (__attribute__((address_space(3))) void*)l, 16, 0, 0);
}

// ---------------- batched f32 -> bf16 conversion (small tensors) ----------------
struct CvtTab {
    const float* src[8];
    ushort* dst[8];
    unsigned cum[9];
};

__global__ void cvt_bf16(CvtTab t, unsigned total4) {
    unsigned stride = gridDim.x * blockDim.x;
    for (unsigned i = blockIdx.x * blockDim.x + threadIdx.x; i < total4; i += stride) {
        int j = 0;
        while (i >= t.cum[j + 1]) ++j;
        unsigned off = i - t.cum[j];
        float4 v = reinterpret_cast<const float4*>(t.src[j])[off];
        uint2 o;
        o.x = pack_bf16x2(v.x, v.y);
        o.y = pack_bf16x2(v.z, v.w);
        reinterpret_cast<uint2*>(t.dst[j])[off] = o;
    }
}

// ------- batched f32 -> fp8 e4m3, PACKED-PAIR layout (score feats + weights) -------
// Within each 64B K-segment of a row, 16B slot p = { fp8 of k[p*8..p*8+8) of half0,
// fp8 of k[32+p*8..+8) of half1 }. One ds_read_b128 yields BOTH ks operands.
struct Cvt8Tab {
    const float* src[8];
    uchar* dst[8];
    unsigned cum[9];   // cumulative 16-byte output chunks
};

__device__ __forceinline__ uint pk8(float4 v) {
    int r = __builtin_amdgcn_cvt_pk_fp8_f32(v.x, v.y, 0, false);
    r = __builtin_amdgcn_cvt_pk_fp8_f32(v.z, v.w, r, true);
    return (uint)r;
}

__global__ void cvt_fp8(Cvt8Tab t, unsigned total16) {
    unsigned stride = gridDim.x * blockDim.x;
    for (unsigned i = blockIdx.x * blockDim.x + threadIdx.x; i < total16; i += stride) {
        int j = 0;
        while (i >= t.cum[j + 1]) ++j;
        unsigned o = i - t.cum[j];
        unsigned row = o >> 6, c = o & 63, tt = c >> 2, pp = c & 3;
        const float* s0 = t.src[j] + (size_t)row * 1024 + tt * 64 + pp * 8;
        float4 a0 = *(const float4*)(s0);
        float4 a1 = *(const float4*)(s0 + 4);
        float4 b0 = *(const float4*)(s0 + 32);
        float4 b1 = *(const float4*)(s0 + 36);
        uint4 ov;
        ov.x = pk8(a0); ov.y = pk8(a1); ov.z = pk8(b0); ov.w = pk8(b1);
        *reinterpret_cast<uint4*>(t.dst[j] + (size_t)o * 16) = ov;
    }
}

// ======== fp8 score GEMM: 512 thr, 256x256 tile, BK=128, dbuf 128KB ========
// R12 geometry (packed-pair fp8, measured-zero-conflict b128 reads) with BK=128:
// per tile stage 8 gloads (two packed 64B K-segments/row), 24 b128 reads, 128 MFMA,
// ONE vmcnt(0)+barrier. Halves the count of drain/barrier events: per-tile cost is
// dominated by a byte-independent fixed component F~3000cyc (R3-vs-R12 evidence:
// halving bytes+loads only cut 680cyc/tile), so amortizing F over 2x work wins.
// LDS buf d @ d*65536: A kh0 @0, A kh1 @16384, W kh0 @32768, W kh1 @49152.
struct PArgs {
    const uchar* A[2];
    const uchar* Wa[2];
    const uchar* Wb[2];
    const float* qa[2];
    const float* qb[2];
    const float* va[2];
    const float* vb[2];
    float* oa[2];
    float* ob[2];
};

__global__ __launch_bounds__(512, 1) void gemm_pipe8(PArgs P, int nmul, int nbadd,
                                                     int bshift, int brshift)
{
    extern __shared__ char smem[];

    const int tid = threadIdx.x;
    const int lane = tid & 63, wv = tid >> 6;
    const int wr = wv >> 2, wc = wv & 3;
    const int lrow = lane & 15, lk = lane >> 4;

    const int br = blockIdx.x >> brshift;
    const int m0 = (blockIdx.x & ((1 << brshift) - 1)) << 8;
    const int na = blockIdx.y * nmul;
    const int nb = na + nbadd;

    const uchar* A  = P.A[br];
    const uchar* Wa = P.Wa[br];
    const uchar* Wb = P.Wb[br];

    // staging map: thread t -> row r = u*128 + (t>>2), 16B slot s=(t&3);
    // stored slot s holds packed chunk c = s ^ ((r>>1)&3) = (t&3) ^ ((t>>3)&3).
    const int rr = tid >> 2;
    const int c  = (tid & 3) ^ ((tid >> 3) & 3);
    const uchar* sA0 = A  + (size_t)(m0 + rr) * 1024 + c * 16;
    const uchar* sA1 = A  + (size_t)(m0 + 128 + rr) * 1024 + c * 16;
    const uchar* sW0 = Wa + (size_t)(na + rr) * 1024 + c * 16;
    const uchar* sW1 = Wb + (size_t)(nb + rr) * 1024 + c * 16;

    auto stage = [&](int t, int d) {
        char* b = smem + d * 65536 + tid * 16;
        size_t k = (size_t)t * 128;
        #pragma unroll
        for (int kh = 0; kh < 2; ++kh) {
            gload16(sA0 + k + kh * 64, b + kh * 16384);
            gload16(sA1 + k + kh * 64, b + kh * 16384 + 8192);
            gload16(sW0 + k + kh * 64, b + 32768 + kh * 16384);
            gload16(sW1 + k + kh * 64, b + 32768 + kh * 16384 + 8192);
        }
    };

    auto rdA = [&](int d, int kh, int mi) -> lx2 {
        int row = wr * 128 + mi * 16 + lrow;
        return *(const lx2*)(smem + d * 65536 + kh * 16384 + row * 64 +
                             ((lk ^ ((row >> 1) & 3)) << 4));
    };
    auto rdB = [&](int d, int kh, int ni) -> lx2 {
        int row = wc * 64 + ni * 16 + lrow;
        return *(const lx2*)(smem + d * 65536 + 32768 + kh * 16384 + row * 64 +
                             ((lk ^ ((row >> 1) & 3)) << 4));
    };

    f32x4 acc[8][4];
    #pragma unroll
    for (int i = 0; i < 8; ++i)
        #pragma unroll
        for (int j = 0; j < 4; ++j) { f32x4 z = {0.f,0.f,0.f,0.f}; acc[i][j] = z; }

    // prologue: stage tile 0
    stage(0, 0);
    asm volatile("s_waitcnt vmcnt(0)" ::: "memory");
    __syncthreads();

    auto body = [&](int t, int cur, int nxt, bool pf) {
        if (pf) stage(t + 1, nxt);   // burst-issue next tile's staging
        #pragma unroll
        for (int kh = 0; kh < 2; ++kh) {
            lx2 af[4], bfr[4];
            #pragma unroll
            for (int ni = 0; ni < 4; ++ni) bfr[ni] = rdB(cur, kh, ni);
            #pragma unroll
            for (int mi = 0; mi < 4; ++mi) af[mi] = rdA(cur, kh, mi);
            __builtin_amdgcn_s_setprio(1);
            #pragma unroll
            for (int mi = 0; mi < 4; ++mi)
                #pragma unroll
                for (int ni = 0; ni < 4; ++ni) {
                    acc[mi][ni] = __builtin_amdgcn_mfma_f32_16x16x32_fp8_fp8(af[mi][0], bfr[ni][0], acc[mi][ni], 0, 0, 0);
                    acc[mi][ni] = __builtin_amdgcn_mfma_f32_16x16x32_fp8_fp8(af[mi][1], bfr[ni][1], acc[mi][ni], 0, 0, 0);
                }
            __builtin_amdgcn_s_setprio(0);
            #pragma unroll
            for (int mi = 0; mi < 4; ++mi) af[mi] = rdA(cur, kh, mi + 4);
            __builtin_amdgcn_s_setprio(1);
            #pragma unroll
            for (int mi = 0; mi < 4; ++mi)
                #pragma unroll
                for (int ni = 0; ni < 4; ++ni) {
                    acc[mi + 4][ni] = __builtin_amdgcn_mfma_f32_16x16x32_fp8_fp8(af[mi][0], bfr[ni][0], acc[mi + 4][ni], 0, 0, 0);
                    acc[mi + 4][ni] = __builtin_amdgcn_mfma_f32_16x16x32_fp8_fp8(af[mi][1], bfr[ni][1], acc[mi + 4][ni], 0, 0, 0);
                }
            __builtin_amdgcn_s_setprio(0);
        }
        // ---- tile end: drain next tile's loads, barrier
        asm volatile("s_waitcnt vmcnt(0)" ::: "memory");
        __syncthreads();
    };

    #pragma unroll 1
    for (int tt = 0; tt < 4; ++tt) {
        body(2 * tt,     0, 1, true);
        body(2 * tt + 1, 1, 0, tt < 3);
    }

    // ---- score epilogue (per-wave side: wc<2 -> a, else -> b) ----
    const float* qsrc = (wc < 2) ? P.qa[br] : P.qb[br];
    const float* vsrc = (wc < 2) ? P.va[br] : P.vb[br];
    float* osrc       = (wc < 2) ? P.oa[br] : P.ob[br];
    const int nbase0 = ((wc < 2) ? na : nb) + (wc & 1) * 64;
    #pragma unroll
    for (int mi = 0; mi < 8; ++mi) {
        int mbase = m0 + wr * 128 + mi * 16;
        int bb = mbase >> bshift;
        const float* qrow = qsrc + (size_t)bb * 1024;
        float part[4] = {0.f, 0.f, 0.f, 0.f};
        #pragma unroll
        for (int ni = 0; ni < 4; ++ni) {
            int nn = nbase0 + ni * 16 + lrow;
            float qn = qrow[nn], vn = vsrc[nn];
            #pragma unroll
            for (int r2 = 0; r2 < 4; ++r2)
                part[r2] += fast_tanh(acc[mi][ni][r2] + qn) * vn;
        }
        #pragma unroll
        for (int off = 1; off < 16; off <<= 1)
            #pragma unroll
            for (int r2 = 0; r2 < 4; ++r2)
                part[r2] += __shfl_xor(part[r2], off, 64);
        if (lrow == 0) {
            #pragma unroll
            for (int r2 = 0; r2 < 4; ++r2)
                atomicAdd(&osrc[mbase + lk * 4 + r2], part[r2]);
        }
    }
}

// ============ fused 4-way q-projection: q = x @ W^T + b  (bf16, M=128) ============
struct QArgs {
    const ushort* A[4];
    const ushort* W[4];
    const float* bias[4];
    float* out[4];
};

__global__ __launch_bounds__(256, 2) void gemm_q(QArgs Q)
{
    __shared__ char smemq[32768];
    char* As = smemq;
    char* Ws = smemq + 16384;

    const int tid = threadIdx.x;
    const int lane = tid & 63, wv = tid >> 6, wr = wv >> 1, wc = wv & 1;
    const int lrow = lane & 15, lk = lane >> 4;
    const int n0 = blockIdx.y << 7;

    const ushort* A = Q.A[blockIdx.x];
    const ushort* W = Q.W[blockIdx.x];

    f32x4 acc[4][4];
    #pragma unroll
    for (int i = 0; i < 4; ++i)
        #pragma unroll
        for (int j = 0; j < 4; ++j) { f32x4 z = {0.f,0.f,0.f,0.f}; acc[i][j] = z; }

    const int srow = tid >> 3;
    const int g = (tid & 7) ^ (srow & 7);
    const ushort* pA = A + (size_t)srow * 1024 + g * 8;
    const ushort* pW = W + (size_t)(n0 + srow) * 1024 + g * 8;

    for (int t = 0; t < 16; ++t) {
        #pragma unroll
        for (int j = 0; j < 4; ++j)
            gload16(pA + (size_t)j * 32768 + (size_t)t * 64, As + j * 4096 + tid * 16);
        #pragma unroll
        for (int j = 0; j < 4; ++j)
            gload16(pW + (size_t)j * 32768 + (size_t)t * 64, Ws + j * 4096 + tid * 16);
        __syncthreads();
        #pragma unroll
        for (int ks = 0; ks < 2; ++ks) {
            bf16x8 af[4], bfr[4];
            const int q = ks * 4 + lk;
            #pragma unroll
            for (int mi = 0; mi < 4; ++mi) {
                int row = wr * 64 + mi * 16 + lrow;
                af[mi] = *(const bf16x8*)(As + row * 128 + ((q ^ (row & 7)) << 4));
            }
            #pragma unroll
            for (int ni = 0; ni < 4; ++ni) {
                int row = wc * 64 + ni * 16 + lrow;
                bfr[ni] = *(const bf16x8*)(Ws + row * 128 + ((q ^ (row & 7)) << 4));
            }
            #pragma unroll
            for (int mi = 0; mi < 4; ++mi)
                #pragma unroll
                for (int ni = 0; ni < 4; ++ni)
                    acc[mi][ni] = __builtin_amdgcn_mfma_f32_16x16x32_bf16(af[mi], bfr[ni], acc[mi][ni], 0, 0, 0);
        }
        __syncthreads();
    }

    float* out = Q.out[blockIdx.x];
    const float* bias = Q.bias[blockIdx.x];
    #pragma unroll
    for (int mi = 0; mi < 4; ++mi) {
        int mrow0 = wr * 64 + mi * 16 + lk * 4;
        #pragma unroll
        for (int ni = 0; ni < 4; ++ni) {
            int n = n0 + wc * 64 + ni * 16 + lrow;
            float bv = bias[n];
            #pragma unroll
            for (int r = 0; r < 4; ++r)
                out[(size_t)(mrow0 + r) * 1024 + n] = acc[mi][ni][r] + bv;
        }
    }
}

// ============ final GEMM (split-K, atomic, bf16) ============
__global__ __launch_bounds__(256, 2) void gemm_fin(
    const ushort* A, const ushort* W, const float* bias, float* out, int K, int kchunk)
{
    __shared__ char smemf[32768];
    char* As = smemf;
    char* Ws = smemf + 16384;

    const int tid = threadIdx.x;
    const int lane = tid & 63, wv = tid >> 6, wr = wv >> 1, wc = wv & 1;
    const int lrow = lane & 15, lk = lane >> 4;
    const int n0 = blockIdx.y << 7;
    const int nkt = kchunk >> 6;
    const int ktbase = blockIdx.z * nkt;

    f32x4 acc[4][4];
    #pragma unroll
    for (int i = 0; i < 4; ++i)
        #pragma unroll
        for (int j = 0; j < 4; ++j) { f32x4 z = {0.f,0.f,0.f,0.f}; acc[i][j] = z; }

    const int srow = tid >> 3;
    const int g = (tid & 7) ^ (srow & 7);
    const ushort* pA = A + (size_t)srow * K + ktbase * 64 + g * 8;
    const ushort* pW = W + (size_t)(n0 + srow) * K + ktbase * 64 + g * 8;

    for (int t = 0; t < nkt; ++t) {
        #pragma unroll
        for (int j = 0; j < 4; ++j)
            gload16(pA + (size_t)j * 32 * K + (size_t)t * 64, As + j * 4096 + tid * 16);
        #pragma unroll
        for (int j = 0; j < 4; ++j)
            gload16(pW + (size_t)j * 32 * K + (size_t)t * 64, Ws + j * 4096 + tid * 16);
        __syncthreads();
        #pragma unroll
        for (int ks = 0; ks < 2; ++ks) {
            bf16x8 af[4], bfr[4];
            const int q = ks * 4 + lk;
            #pragma unroll
            for (int mi = 0; mi < 4; ++mi) {
                int row = wr * 64 + mi * 16 + lrow;
                af[mi] = *(const bf16x8*)(As + row * 128 + ((q ^ (row & 7)) << 4));
            }
            #pragma unroll
            for (int ni = 0; ni < 4; ++ni) {
                int row = wc * 64 + ni * 16 + lrow;
                bfr[ni] = *(const bf16x8*)(Ws + row * 128 + ((q ^ (row & 7)) << 4));
            }
            #pragma unroll
            for (int mi = 0; mi < 4; ++mi)
                #pragma unroll
                for (int ni = 0; ni < 4; ++ni)
                    acc[mi][ni] = __builtin_amdgcn_mfma_f32_16x16x32_bf16(af[mi], bfr[ni], acc[mi][ni], 0, 0, 0);
        }
        __syncthreads();
    }

    #pragma unroll
    for (int mi = 0; mi < 4; ++mi) {
        int mrow0 = wr * 64 + mi * 16 + lk * 4;
        #pragma unroll
        for (int ni = 0; ni < 4; ++ni) {
            int n = n0 + wc * 64 + ni * 16 + lrow;
            float bv = (blockIdx.z == 0) ? bias[n] : 0.f;
            #pragma unroll
            for (int r = 0; r < 4; ++r)
                atomicAdd(&out[(size_t)(mrow0 + r) * 1024 + n], acc[mi][ni][r] + bv);
        }
    }
}

// ---------------- softmax + context, image branches (f32 feats) ----------------
__global__ void softmax_ctx_img(const float* __restrict__ iof, const float* __restrict__ ipf,
                                const float* __restrict__ sc_io, const float* __restrict__ sc_ip,
                                ushort* __restrict__ combined)
{
    int b = blockIdx.x, br = blockIdx.y;
    const float* A  = br ? ipf : iof;
    const float* sc = br ? sc_ip : sc_io;
    __shared__ float dist[64];
    int tid = threadIdx.x;
    if (tid < 64) {
        float s  = sc[b * 64 + tid];
        float mx = wredmax(s);
        float e  = __expf(s - mx);
        float sm = wredsum(e);
        dist[tid] = e / sm;
    }
    __syncthreads();
    int d0 = tid * 4;
    float a0 = 0, a1 = 0, a2 = 0, a3 = 0;
    const float* base = A + (size_t)b * 64 * 1024 + d0;
    #pragma unroll 4
    for (int n = 0; n < 64; ++n) {
        float w = dist[n];
        float4 t = *(const float4*)(base + (size_t)n * 1024);
        a0 += w * t.x; a1 += w * t.y; a2 += w * t.z; a3 += w * t.w;
    }
    uint2 o;
    o.x = pack_bf16x2(a0, a1);
    o.y = pack_bf16x2(a2, a3);
    *(uint2*)(combined + (size_t)b * 4096 + br * 1024 + d0) = o;
}

// ------- masked softmax + context, text branches (f32 feats; d-split grid y) -------
__global__ void softmax_ctx_text(const float* __restrict__ tf,
                                 const float* __restrict__ sc_to, const float* __restrict__ sc_tp,
                                 const float* __restrict__ mask, ushort* __restrict__ combined)
{
    int b = blockIdx.x;
    __shared__ float d3[256], d4[256], red[8];
    int tid = threadIdx.x, lane = tid & 63, wv = tid >> 6;
    float s3 = sc_to[b * 256 + tid], s4 = sc_tp[b * 256 + tid], m = mask[b * 256 + tid];
    float m3 = wredmax(s3), m4 = wredmax(s4);
    if (lane == 0) { red[wv] = m3; red[4 + wv] = m4; }
    __syncthreads();
    m3 = fmaxf(fmaxf(red[0], red[1]), fmaxf(red[2], red[3]));
    m4 = fmaxf(fmaxf(red[4], red[5]), fmaxf(red[6], red[7]));
    float e3 = __expf(s3 - m3) * m, e4 = __expf(s4 - m4) * m;
    float t3 = wredsum(e3), t4 = wredsum(e4);
    __syncthreads();
    if (lane == 0) { red[wv] = t3; red[4 + wv] = t4; }
    __syncthreads();
    t3 = red[0] + red[1] + red[2] + red[3];
    t4 = red[4] + red[5] + red[6] + red[7];
    d3[tid] = e3 / t3; d4[tid] = e4 / t4;
    __syncthreads();
    // d-split: block y handles 512 cols; 2 f32/thread (8B coalesced)
    int d0 = blockIdx.y * 512 + tid * 2;
    float a0 = 0, a1 = 0, c0 = 0, c1 = 0;
    const float* base = tf + (size_t)b * 256 * 1024 + d0;
    #pragma unroll 4
    for (int l = 0; l < 256; ++l) {
        float w3 = d3[l], w4 = d4[l];
        float2 t = *(const float2*)(base + (size_t)l * 1024);
        a0 += w3 * t.x; a1 += w3 * t.y;
        c0 += w4 * t.x; c1 += w4 * t.y;
    }
    *(uint*)(combined + (size_t)b * 4096 + 2048 + d0) = pack_bf16x2(a0, a1);
    *(uint*)(combined + (size_t)b * 4096 + 3072 + d0) = pack_bf16x2(c0, c1);
}

extern "C" void kernel_launch(void* const* d_in, const int* in_sizes, int n_in,
                              void* d_out, int out_size, void* d_ws, size_t ws_size,
                              hipStream_t stream) {
    const float* text_feat        = (const float*)d_in[0];
    const float* text_feats       = (const float*)d_in[1];
    const float* img_object_feat  = (const float*)d_in[2];
    const float* img_object_feats = (const float*)d_in[3];
    const float* img_place_feat   = (const float*)d_in[4];
    const float* img_place_feats  = (const float*)d_in[5];
    const float* src_mask         = (const float*)d_in[6];
    const float* v_to  = (const float*)d_in[7];
    const float* v_tp  = (const float*)d_in[8];
    const float* v_io  = (const float*)d_in[9];
    const float* v_ip  = (const float*)d_in[10];
    const float* W_t2o = (const float*)d_in[11];
    const float* W_t2p = (const float*)d_in[12];
    const float* W_o2t = (const float*)d_in[13];
    const float* W_p2t = (const float*)d_in[14];
    const float* W_oo  = (const float*)d_in[15];
    const float* b_oo  = (const float*)d_in[16];
    const float* W_pp  = (const float*)d_in[17];
    const float* b_pp  = (const float*)d_in[18];
    const float* W_tot = (const float*)d_in[19];
    const float* b_tot = (const float*)d_in[20];
    const float* W_tpt = (const float*)d_in[21];
    const float* b_tpt = (const float*)d_in[22];
    const float* W_out = (const float*)d_in[23];
    const float* b_out = (const float*)d_in[24];

    // ---- workspace layout ----
    char* p = (char*)d_ws;
    auto alloc = [&](size_t bytes) { char* r = p; p += (bytes + 255) & ~(size_t)255; return r; };
    ushort* wq_oo  = (ushort*)alloc((size_t)1024 * 1024 * 2);
    ushort* wq_pp  = (ushort*)alloc((size_t)1024 * 1024 * 2);
    ushort* wq_tot = (ushort*)alloc((size_t)1024 * 1024 * 2);
    ushort* wq_tpt = (ushort*)alloc((size_t)1024 * 1024 * 2);
    ushort* wb_out = (ushort*)alloc((size_t)1024 * 4096 * 2);
    ushort* tfq_bf  = (ushort*)alloc((size_t)128 * 1024 * 2);
    ushort* iofq_bf = (ushort*)alloc((size_t)128 * 1024 * 2);
    ushort* ipfq_bf = (ushort*)alloc((size_t)128 * 1024 * 2);
    uchar* w8_t2o = (uchar*)alloc((size_t)1024 * 1024);
    uchar* w8_t2p = (uchar*)alloc((size_t)1024 * 1024);
    uchar* w8_o2t = (uchar*)alloc((size_t)1024 * 1024);
    uchar* w8_p2t = (uchar*)alloc((size_t)1024 * 1024);
    uchar* tf8  = (uchar*)alloc((size_t)32768 * 1024);
    uchar* iof8 = (uchar*)alloc((size_t)8192 * 1024);
    uchar* ipf8 = (uchar*)alloc((size_t)8192 * 1024);
    float* q_tot = (float*)alloc((size_t)128 * 1024 * 4);
    float* q_tpt = (float*)alloc((size_t)128 * 1024 * 4);
    float* q_oo  = (float*)alloc((size_t)128 * 1024 * 4);
    float* q_pp  = (float*)alloc((size_t)128 * 1024 * 4);
    float* scores = (float*)alloc((size_t)(8192 * 2 + 32768 * 2) * 4);
    float* sc_io = scores, *sc_ip = scores + 8192, *sc_to = scores + 16384, *sc_tp = scores + 49152;
    ushort* comb_bf = (ushort*)alloc((size_t)128 * 4096 * 2);

    // ---- 1a) f32 -> fp8 packed-pair (score feats + weights) ----
    Cvt8Tab t8;
    const float* s8[7] = { W_t2o, W_t2p, W_o2t, W_p2t, text_feats, img_object_feats, img_place_feats };
    uchar* d8[7] = { w8_t2o, w8_t2p, w8_o2t, w8_p2t, tf8, iof8, ipf8 };
    unsigned n16[7] = { 65536, 65536, 65536, 65536, 2097152, 524288, 524288 };
    unsigned cum8 = 0;
    for (int i = 0; i < 7; ++i) { t8.src[i] = s8[i]; t8.dst[i] = d8[i]; t8.cum[i] = cum8; cum8 += n16[i]; }
    t8.src[7] = nullptr; t8.dst[7] = nullptr; t8.cum[7] = cum8; t8.cum[8] = cum8;
    cvt_fp8<<<4096, 256, 0, stream>>>(t8, cum8);

    // ---- 1b) f32 -> bf16 (q-path weights, W_out, q-input feats) ----
    CvtTab tb;
    const float* sb[8] = { W_oo, W_pp, W_tot, W_tpt, W_out, text_feat, img_object_feat, img_place_feat };
    ushort* db[8] = { wq_oo, wq_pp, wq_tot, wq_tpt, wb_out, tfq_bf, iofq_bf, ipfq_bf };
    unsigned nb4[8] = { 262144, 262144, 262144, 262144, 1048576, 32768, 32768, 32768 };
    unsigned cumb = 0;
    for (int i = 0; i < 8; ++i) { tb.src[i] = sb[i]; tb.dst[i] = db[i]; tb.cum[i] = cumb; cumb += nb4[i]; }
    tb.cum[8] = cumb;
    cvt_bf16<<<2048, 256, 0, stream>>>(tb, cumb);

    // ---- 2) zero atomic targets ----
    hipMemsetAsync(scores, 0, (size_t)(8192 * 2 + 32768 * 2) * 4, stream);
    hipMemsetAsync(d_out, 0, (size_t)128 * 1024 * 4, stream);

    // ---- 3) fused q projections (bf16) ----
    QArgs qa;
    qa.A[0] = tfq_bf;  qa.W[0] = wq_tot; qa.bias[0] = b_tot; qa.out[0] = q_tot;
    qa.A[1] = tfq_bf;  qa.W[1] = wq_tpt; qa.bias[1] = b_tpt; qa.out[1] = q_tpt;
    qa.A[2] = iofq_bf; qa.W[2] = wq_oo;  qa.bias[2] = b_oo;  qa.out[2] = q_oo;
    qa.A[3] = ipfq_bf; qa.W[3] = wq_pp;  qa.bias[3] = b_pp;  qa.out[3] = q_pp;
    gemm_q<<<dim3(4, 8), 256, 0, stream>>>(qa);

    // ---- 4) score GEMMs (fp8 packed-pair, BK=128, 128KB dbuf) ----
    PArgs pi;
    pi.A[0] = iof8;   pi.Wa[0] = w8_o2t; pi.Wb[0] = w8_o2t;
    pi.qa[0] = q_tot; pi.qb[0] = q_tot;  pi.va[0] = v_to; pi.vb[0] = v_to;
    pi.oa[0] = sc_io; pi.ob[0] = sc_io;
    pi.A[1] = ipf8;   pi.Wa[1] = w8_p2t; pi.Wb[1] = w8_p2t;
    pi.qa[1] = q_tpt; pi.qb[1] = q_tpt;  pi.va[1] = v_tp; pi.vb[1] = v_tp;
    pi.oa[1] = sc_ip; pi.ob[1] = sc_ip;
    gemm_pipe8<<<dim3(64, 4), 512, 131072, stream>>>(pi, 256, 128, 6, 5);

    PArgs pt;
    pt.A[0] = tf8;    pt.Wa[0] = w8_t2o; pt.Wb[0] = w8_t2p;
    pt.qa[0] = q_oo;  pt.qb[0] = q_pp;   pt.va[0] = v_io; pt.vb[0] = v_ip;
    pt.oa[0] = sc_to; pt.ob[0] = sc_tp;
    pt.A[1] = pt.A[0]; pt.Wa[1] = pt.Wa[0]; pt.Wb[1] = pt.Wb[0];
    pt.qa[1] = pt.qa[0]; pt.qb[1] = pt.qb[0]; pt.va[1] = pt.va[0]; pt.vb[1] = pt.vb[0];
    pt.oa[1] = pt.oa[0]; pt.ob[1] = pt.ob[0];
    gemm_pipe8<<<dim3(128, 8), 512, 131072, stream>>>(pt, 128, 0, 8, 7);

    // ---- 5) softmax + context (f32 feats) -> combined (bf16) ----
    softmax_ctx_img<<<dim3(128, 2), 256, 0, stream>>>(img_object_feats, img_place_feats, sc_io, sc_ip, comb_bf);
    softmax_ctx_text<<<dim3(128, 2), 256, 0, stream>>>(text_feats, sc_to, sc_tp, src_mask, comb_bf);

    // ---- 6) out = combined @ W_out^T + b_out (split-K=8, atomic) ----
    gemm_fin<<<dim3(1, 8, 8), 256, 0, stream>>>(comb_bf, wb_out, b_out, (float*)d_out, 4096, 512);
}

// Round 14
// 274.414 us; speedup vs baseline: 1.1065x; 1.1065x over previous
//
#include <hip/hip_runtime.h>
#include <hip/hip_bf16.h>

typedef __attribute__((ext_vector_type(8))) short bf16x8;
typedef __attribute__((ext_vector_type(4))) float f32x4;
typedef __attribute__((ext_vector_type(2))) long lx2;

__device__ __forceinline__ uint pack_bf16x2(float a, float b) {
    __hip_bfloat162 p = __float22bfloat162_rn(make_float2(a, b));
    union { __hip_bfloat162 h; uint u; } c; c.h = p; return c.u;
}

__device__ __forceinline__ float fast_tanh(float x) {
    float e = __expf(2.f * x);
    return 1.f - 2.f * __builtin_amdgcn_rcpf(e + 1.f);
}

__device__ __forceinline__ float wredmax(float v) {
    #pragma unroll
    for (int o = 32; o; o >>= 1) v = fmaxf(v, __shfl_xor(v, o, 64));
    return v;
}
__device__ __forceinline__ float wredsum(float v) {
    #pragma unroll
    for (int o = 32; o; o >>= 1) v += __shfl_xor(v, o, 64);
    return v;
}

__device__ __forceinline__ void gload16(const void* g, void* l) {
    __builtin_amdgcn_global_load_lds(
        (const __attribute__((address_space(1))) void*)g,
        (__attribute__((address_space(3))) void*)l, 16, 0, 0);
}

// ---------------- fused batched conversion: f32->fp8 packed-pair, then f32->bf16 ----------------
struct Cvt8Tab {
    const float* src[8];
    uchar* dst[8];
    unsigned cum[9];   // cumulative 16-byte output chunks
};
struct CvtTab {
    const float* src[8];
    ushort* dst[8];
    unsigned cum[9];   // cumulative float4 chunks
};

__device__ __forceinline__ uint pk8(float4 v) {
    int r = __builtin_amdgcn_cvt_pk_fp8_f32(v.x, v.y, 0, false);
    r = __builtin_amdgcn_cvt_pk_fp8_f32(v.z, v.w, r, true);
    return (uint)r;
}

__global__ void cvt_all(Cvt8Tab t8, unsigned total8, CvtTab tb, unsigned totalb) {
    unsigned stride = gridDim.x * blockDim.x;
    unsigned total = total8 + totalb;
    for (unsigned i = blockIdx.x * blockDim.x + threadIdx.x; i < total; i += stride) {
        if (i < total8) {
            int j = 0;
            while (i >= t8.cum[j + 1]) ++j;
            unsigned o = i - t8.cum[j];
            unsigned row = o >> 6, c = o & 63, tt = c >> 2, pp = c & 3;
            const float* s0 = t8.src[j] + (size_t)row * 1024 + tt * 64 + pp * 8;
            float4 a0 = *(const float4*)(s0);
            float4 a1 = *(const float4*)(s0 + 4);
            float4 b0 = *(const float4*)(s0 + 32);
            float4 b1 = *(const float4*)(s0 + 36);
            uint4 ov;
            ov.x = pk8(a0); ov.y = pk8(a1); ov.z = pk8(b0); ov.w = pk8(b1);
            *reinterpret_cast<uint4*>(t8.dst[j] + (size_t)o * 16) = ov;
        } else {
            unsigned ii = i - total8;
            int j = 0;
            while (ii >= tb.cum[j + 1]) ++j;
            unsigned off = ii - tb.cum[j];
            float4 v = reinterpret_cast<const float4*>(tb.src[j])[off];
            uint2 o;
            o.x = pack_bf16x2(v.x, v.y);
            o.y = pack_bf16x2(v.z, v.w);
            reinterpret_cast<uint2*>(tb.dst[j])[off] = o;
        }
    }
}

// ======== fp8 score GEMM: 512 thr, 256x256 tile, BK=64, dbuf 64KB (R12 core) ========
// Packed-pair fp8 layout -> measured-zero-conflict b128 LDS reads; burst stage at
// tile top, one vmcnt(0)+barrier per tile. ~48% MFMA-pipe-bound at this point
// (512 waves-MFMA x 4.85cyc = 2480 of 5130 cyc/tile; MfmaUtil ~40-42 agrees).
struct PArgs {
    const uchar* A[2];
    const uchar* Wa[2];
    const uchar* Wb[2];
    const float* qa[2];
    const float* qb[2];
    const float* va[2];
    const float* vb[2];
    float* oa[2];
    float* ob[2];
};

__global__ __launch_bounds__(512, 1) void gemm_pipe8(PArgs P, int nmul, int nbadd,
                                                     int bshift, int brshift)
{
    extern __shared__ char smem[];   // buf d: A @ d*32768 (16KB), W @ +16384 (16KB)

    const int tid = threadIdx.x;
    const int lane = tid & 63, wv = tid >> 6;
    const int wr = wv >> 2, wc = wv & 3;
    const int lrow = lane & 15, lk = lane >> 4;

    const int br = blockIdx.x >> brshift;
    const int m0 = (blockIdx.x & ((1 << brshift) - 1)) << 8;
    const int na = blockIdx.y * nmul;
    const int nb = na + nbadd;

    const uchar* A  = P.A[br];
    const uchar* Wa = P.Wa[br];
    const uchar* Wb = P.Wb[br];

    // staging map: thread t -> row r = u*128 + (t>>2), 16B slot s=(t&3);
    // stored slot s holds packed chunk c = s ^ ((r>>1)&3) = (t&3) ^ ((t>>3)&3).
    const int rr = tid >> 2;
    const int c  = (tid & 3) ^ ((tid >> 3) & 3);
    const uchar* sA0 = A  + (size_t)(m0 + rr) * 1024 + c * 16;
    const uchar* sA1 = A  + (size_t)(m0 + 128 + rr) * 1024 + c * 16;
    const uchar* sW0 = Wa + (size_t)(na + rr) * 1024 + c * 16;
    const uchar* sW1 = Wb + (size_t)(nb + rr) * 1024 + c * 16;

    auto stage = [&](int t, int d) {
        char* b = smem + d * 32768 + tid * 16;
        size_t k = (size_t)t * 64;
        gload16(sA0 + k, b);
        gload16(sA1 + k, b + 8192);
        gload16(sW0 + k, b + 16384);
        gload16(sW1 + k, b + 24576);
    };

    auto rdA = [&](int d, int mi) -> lx2 {
        int row = wr * 128 + mi * 16 + lrow;
        return *(const lx2*)(smem + d * 32768 + row * 64 +
                             ((lk ^ ((row >> 1) & 3)) << 4));
    };
    auto rdB = [&](int d, int ni) -> lx2 {
        int row = wc * 64 + ni * 16 + lrow;
        return *(const lx2*)(smem + d * 32768 + 16384 + row * 64 +
                             ((lk ^ ((row >> 1) & 3)) << 4));
    };

    f32x4 acc[8][4];
    #pragma unroll
    for (int i = 0; i < 8; ++i)
        #pragma unroll
        for (int j = 0; j < 4; ++j) { f32x4 z = {0.f,0.f,0.f,0.f}; acc[i][j] = z; }

    // prologue: stage tile 0
    stage(0, 0);
    asm volatile("s_waitcnt vmcnt(0)" ::: "memory");
    __syncthreads();

    auto body = [&](int t, int cur, int nxt, bool pf) {
        lx2 af[4], bfr[4];
        if (pf) stage(t + 1, nxt);   // burst-issue next tile's staging
        #pragma unroll
        for (int ni = 0; ni < 4; ++ni) bfr[ni] = rdB(cur, ni);
        #pragma unroll
        for (int mi = 0; mi < 4; ++mi) af[mi] = rdA(cur, mi);
        __builtin_amdgcn_s_setprio(1);
        #pragma unroll
        for (int mi = 0; mi < 4; ++mi)
            #pragma unroll
            for (int ni = 0; ni < 4; ++ni) {
                acc[mi][ni] = __builtin_amdgcn_mfma_f32_16x16x32_fp8_fp8(af[mi][0], bfr[ni][0], acc[mi][ni], 0, 0, 0);
                acc[mi][ni] = __builtin_amdgcn_mfma_f32_16x16x32_fp8_fp8(af[mi][1], bfr[ni][1], acc[mi][ni], 0, 0, 0);
            }
        __builtin_amdgcn_s_setprio(0);
        #pragma unroll
        for (int mi = 0; mi < 4; ++mi) af[mi] = rdA(cur, mi + 4);
        __builtin_amdgcn_s_setprio(1);
        #pragma unroll
        for (int mi = 0; mi < 4; ++mi)
            #pragma unroll
            for (int ni = 0; ni < 4; ++ni) {
                acc[mi + 4][ni] = __builtin_amdgcn_mfma_f32_16x16x32_fp8_fp8(af[mi][0], bfr[ni][0], acc[mi + 4][ni], 0, 0, 0);
                acc[mi + 4][ni] = __builtin_amdgcn_mfma_f32_16x16x32_fp8_fp8(af[mi][1], bfr[ni][1], acc[mi + 4][ni], 0, 0, 0);
            }
        __builtin_amdgcn_s_setprio(0);
        asm volatile("s_waitcnt vmcnt(0)" ::: "memory");
        __syncthreads();
    };

    #pragma unroll 1
    for (int tt = 0; tt < 8; ++tt) {
        body(2 * tt,     0, 1, true);
        body(2 * tt + 1, 1, 0, tt < 7);
    }

    // ---- score epilogue (per-wave side: wc<2 -> a, else -> b) ----
    const float* qsrc = (wc < 2) ? P.qa[br] : P.qb[br];
    const float* vsrc = (wc < 2) ? P.va[br] : P.vb[br];
    float* osrc       = (wc < 2) ? P.oa[br] : P.ob[br];
    const int nbase0 = ((wc < 2) ? na : nb) + (wc & 1) * 64;
    #pragma unroll
    for (int mi = 0; mi < 8; ++mi) {
        int mbase = m0 + wr * 128 + mi * 16;
        int bb = mbase >> bshift;
        const float* qrow = qsrc + (size_t)bb * 1024;
        float part[4] = {0.f, 0.f, 0.f, 0.f};
        #pragma unroll
        for (int ni = 0; ni < 4; ++ni) {
            int nn = nbase0 + ni * 16 + lrow;
            float qn = qrow[nn], vn = vsrc[nn];
            #pragma unroll
            for (int r2 = 0; r2 < 4; ++r2)
                part[r2] += fast_tanh(acc[mi][ni][r2] + qn) * vn;
        }
        #pragma unroll
        for (int off = 1; off < 16; off <<= 1)
            #pragma unroll
            for (int r2 = 0; r2 < 4; ++r2)
                part[r2] += __shfl_xor(part[r2], off, 64);
        if (lrow == 0) {
            #pragma unroll
            for (int r2 = 0; r2 < 4; ++r2)
                atomicAdd(&osrc[mbase + lk * 4 + r2], part[r2]);
        }
    }
}

// ============ fused 4-way q-projection, split-K z=4 (atomic): q += x @ W^T (+b at z0) ============
struct QArgs {
    const ushort* A[4];
    const ushort* W[4];
    const float* bias[4];
    float* out[4];
};

__global__ __launch_bounds__(256, 2) void gemm_q(QArgs Q, int kchunk)
{
    __shared__ char smemq[32768];
    char* As = smemq;
    char* Ws = smemq + 16384;

    const int tid = threadIdx.x;
    const int lane = tid & 63, wv = tid >> 6, wr = wv >> 1, wc = wv & 1;
    const int lrow = lane & 15, lk = lane >> 4;
    const int n0 = blockIdx.y << 7;
    const int nkt = kchunk >> 6;
    const int ktbase = blockIdx.z * nkt;

    const ushort* A = Q.A[blockIdx.x];
    const ushort* W = Q.W[blockIdx.x];

    f32x4 acc[4][4];
    #pragma unroll
    for (int i = 0; i < 4; ++i)
        #pragma unroll
        for (int j = 0; j < 4; ++j) { f32x4 z = {0.f,0.f,0.f,0.f}; acc[i][j] = z; }

    const int srow = tid >> 3;
    const int g = (tid & 7) ^ (srow & 7);
    const ushort* pA = A + (size_t)srow * 1024 + (size_t)ktbase * 64 + g * 8;
    const ushort* pW = W + (size_t)(n0 + srow) * 1024 + (size_t)ktbase * 64 + g * 8;

    for (int t = 0; t < nkt; ++t) {
        #pragma unroll
        for (int j = 0; j < 4; ++j)
            gload16(pA + (size_t)j * 32768 + (size_t)t * 64, As + j * 4096 + tid * 16);
        #pragma unroll
        for (int j = 0; j < 4; ++j)
            gload16(pW + (size_t)j * 32768 + (size_t)t * 64, Ws + j * 4096 + tid * 16);
        __syncthreads();
        #pragma unroll
        for (int ks = 0; ks < 2; ++ks) {
            bf16x8 af[4], bfr[4];
            const int q = ks * 4 + lk;
            #pragma unroll
            for (int mi = 0; mi < 4; ++mi) {
                int row = wr * 64 + mi * 16 + lrow;
                af[mi] = *(const bf16x8*)(As + row * 128 + ((q ^ (row & 7)) << 4));
            }
            #pragma unroll
            for (int ni = 0; ni < 4; ++ni) {
                int row = wc * 64 + ni * 16 + lrow;
                bfr[ni] = *(const bf16x8*)(Ws + row * 128 + ((q ^ (row & 7)) << 4));
            }
            #pragma unroll
            for (int mi = 0; mi < 4; ++mi)
                #pragma unroll
                for (int ni = 0; ni < 4; ++ni)
                    acc[mi][ni] = __builtin_amdgcn_mfma_f32_16x16x32_bf16(af[mi], bfr[ni], acc[mi][ni], 0, 0, 0);
        }
        __syncthreads();
    }

    float* out = Q.out[blockIdx.x];
    const float* bias = Q.bias[blockIdx.x];
    #pragma unroll
    for (int mi = 0; mi < 4; ++mi) {
        int mrow0 = wr * 64 + mi * 16 + lk * 4;
        #pragma unroll
        for (int ni = 0; ni < 4; ++ni) {
            int n = n0 + wc * 64 + ni * 16 + lrow;
            float bv = (blockIdx.z == 0) ? bias[n] : 0.f;
            #pragma unroll
            for (int r = 0; r < 4; ++r)
                atomicAdd(&out[(size_t)(mrow0 + r) * 1024 + n], acc[mi][ni][r] + bv);
        }
    }
}

// ============ final GEMM (split-K z=16, atomic, bf16) ============
__global__ __launch_bounds__(256, 2) void gemm_fin(
    const ushort* A, const ushort* W, const float* bias, float* out, int K, int kchunk)
{
    __shared__ char smemf[32768];
    char* As = smemf;
    char* Ws = smemf + 16384;

    const int tid = threadIdx.x;
    const int lane = tid & 63, wv = tid >> 6, wr = wv >> 1, wc = wv & 1;
    const int lrow = lane & 15, lk = lane >> 4;
    const int n0 = blockIdx.y << 7;
    const int nkt = kchunk >> 6;
    const int ktbase = blockIdx.z * nkt;

    f32x4 acc[4][4];
    #pragma unroll
    for (int i = 0; i < 4; ++i)
        #pragma unroll
        for (int j = 0; j < 4; ++j) { f32x4 z = {0.f,0.f,0.f,0.f}; acc[i][j] = z; }

    const int srow = tid >> 3;
    const int g = (tid & 7) ^ (srow & 7);
    const ushort* pA = A + (size_t)srow * K + ktbase * 64 + g * 8;
    const ushort* pW = W + (size_t)(n0 + srow) * K + ktbase * 64 + g * 8;

    for (int t = 0; t < nkt; ++t) {
        #pragma unroll
        for (int j = 0; j < 4; ++j)
            gload16(pA + (size_t)j * 32 * K + (size_t)t * 64, As + j * 4096 + tid * 16);
        #pragma unroll
        for (int j = 0; j < 4; ++j)
            gload16(pW + (size_t)j * 32 * K + (size_t)t * 64, Ws + j * 4096 + tid * 16);
        __syncthreads();
        #pragma unroll
        for (int ks = 0; ks < 2; ++ks) {
            bf16x8 af[4], bfr[4];
            const int q = ks * 4 + lk;
            #pragma unroll
            for (int mi = 0; mi < 4; ++mi) {
                int row = wr * 64 + mi * 16 + lrow;
                af[mi] = *(const bf16x8*)(As + row * 128 + ((q ^ (row & 7)) << 4));
            }
            #pragma unroll
            for (int ni = 0; ni < 4; ++ni) {
                int row = wc * 64 + ni * 16 + lrow;
                bfr[ni] = *(const bf16x8*)(Ws + row * 128 + ((q ^ (row & 7)) << 4));
            }
            #pragma unroll
            for (int mi = 0; mi < 4; ++mi)
                #pragma unroll
                for (int ni = 0; ni < 4; ++ni)
                    acc[mi][ni] = __builtin_amdgcn_mfma_f32_16x16x32_bf16(af[mi], bfr[ni], acc[mi][ni], 0, 0, 0);
        }
        __syncthreads();
    }

    #pragma unroll
    for (int mi = 0; mi < 4; ++mi) {
        int mrow0 = wr * 64 + mi * 16 + lk * 4;
        #pragma unroll
        for (int ni = 0; ni < 4; ++ni) {
            int n = n0 + wc * 64 + ni * 16 + lrow;
            float bv = (blockIdx.z == 0) ? bias[n] : 0.f;
            #pragma unroll
            for (int r = 0; r < 4; ++r)
                atomicAdd(&out[(size_t)(mrow0 + r) * 1024 + n], acc[mi][ni][r] + bv);
        }
    }
}

// ---- fused softmax + context: y<2 = text d-halves, y>=2 = img branches (f32 feats) ----
__global__ void softmax_ctx(const float* __restrict__ tf,
                            const float* __restrict__ iof, const float* __restrict__ ipf,
                            const float* __restrict__ sc_to, const float* __restrict__ sc_tp,
                            const float* __restrict__ sc_io, const float* __restrict__ sc_ip,
                            const float* __restrict__ mask, ushort* __restrict__ combined)
{
    int b = blockIdx.x, y = blockIdx.y;
    int tid = threadIdx.x, lane = tid & 63, wv = tid >> 6;
    if (y >= 2) {
        int brn = y - 2;
        const float* A  = brn ? ipf : iof;
        const float* sc = brn ? sc_ip : sc_io;
        __shared__ float dist[64];
        if (tid < 64) {
            float s  = sc[b * 64 + tid];
            float mx = wredmax(s);
            float e  = __expf(s - mx);
            float sm = wredsum(e);
            dist[tid] = e / sm;
        }
        __syncthreads();
        int d0 = tid * 4;
        float a0 = 0, a1 = 0, a2 = 0, a3 = 0;
        const float* base = A + (size_t)b * 64 * 1024 + d0;
        #pragma unroll 4
        for (int n = 0; n < 64; ++n) {
            float w = dist[n];
            float4 t = *(const float4*)(base + (size_t)n * 1024);
            a0 += w * t.x; a1 += w * t.y; a2 += w * t.z; a3 += w * t.w;
        }
        uint2 o;
        o.x = pack_bf16x2(a0, a1);
        o.y = pack_bf16x2(a2, a3);
        *(uint2*)(combined + (size_t)b * 4096 + brn * 1024 + d0) = o;
    } else {
        __shared__ float d3[256], d4[256], red[8];
        float s3 = sc_to[b * 256 + tid], s4 = sc_tp[b * 256 + tid], m = mask[b * 256 + tid];
        float m3 = wredmax(s3), m4 = wredmax(s4);
        if (lane == 0) { red[wv] = m3; red[4 + wv] = m4; }
        __syncthreads();
        m3 = fmaxf(fmaxf(red[0], red[1]), fmaxf(red[2], red[3]));
        m4 = fmaxf(fmaxf(red[4], red[5]), fmaxf(red[6], red[7]));
        float e3 = __expf(s3 - m3) * m, e4 = __expf(s4 - m4) * m;
        float t3 = wredsum(e3), t4 = wredsum(e4);
        __syncthreads();
        if (lane == 0) { red[wv] = t3; red[4 + wv] = t4; }
        __syncthreads();
        t3 = red[0] + red[1] + red[2] + red[3];
        t4 = red[4] + red[5] + red[6] + red[7];
        d3[tid] = e3 / t3; d4[tid] = e4 / t4;
        __syncthreads();
        int d0 = y * 512 + tid * 2;
        float a0 = 0, a1 = 0, c0 = 0, c1 = 0;
        const float* base = tf + (size_t)b * 256 * 1024 + d0;
        #pragma unroll 4
        for (int l = 0; l < 256; ++l) {
            float w3 = d3[l], w4 = d4[l];
            float2 t = *(const float2*)(base + (size_t)l * 1024);
            a0 += w3 * t.x; a1 += w3 * t.y;
            c0 += w4 * t.x; c1 += w4 * t.y;
        }
        *(uint*)(combined + (size_t)b * 4096 + 2048 + d0) = pack_bf16x2(a0, a1);
        *(uint*)(combined + (size_t)b * 4096 + 3072 + d0) = pack_bf16x2(c0, c1);
    }
}

extern "C" void kernel_launch(void* const* d_in, const int* in_sizes, int n_in,
                              void* d_out, int out_size, void* d_ws, size_t ws_size,
                              hipStream_t stream) {
    const float* text_feat        = (const float*)d_in[0];
    const float* text_feats       = (const float*)d_in[1];
    const float* img_object_feat  = (const float*)d_in[2];
    const float* img_object_feats = (const float*)d_in[3];
    const float* img_place_feat   = (const float*)d_in[4];
    const float* img_place_feats  = (const float*)d_in[5];
    const float* src_mask         = (const float*)d_in[6];
    const float* v_to  = (const float*)d_in[7];
    const float* v_tp  = (const float*)d_in[8];
    const float* v_io  = (const float*)d_in[9];
    const float* v_ip  = (const float*)d_in[10];
    const float* W_t2o = (const float*)d_in[11];
    const float* W_t2p = (const float*)d_in[12];
    const float* W_o2t = (const float*)d_in[13];
    const float* W_p2t = (const float*)d_in[14];
    const float* W_oo  = (const float*)d_in[15];
    const float* b_oo  = (const float*)d_in[16];
    const float* W_pp  = (const float*)d_in[17];
    const float* b_pp  = (const float*)d_in[18];
    const float* W_tot = (const float*)d_in[19];
    const float* b_tot = (const float*)d_in[20];
    const float* W_tpt = (const float*)d_in[21];
    const float* b_tpt = (const float*)d_in[22];
    const float* W_out = (const float*)d_in[23];
    const float* b_out = (const float*)d_in[24];

    // ---- workspace layout ----
    char* p = (char*)d_ws;
    auto alloc = [&](size_t bytes) { char* r = p; p += (bytes + 255) & ~(size_t)255; return r; };
    ushort* wq_oo  = (ushort*)alloc((size_t)1024 * 1024 * 2);
    ushort* wq_pp  = (ushort*)alloc((size_t)1024 * 1024 * 2);
    ushort* wq_tot = (ushort*)alloc((size_t)1024 * 1024 * 2);
    ushort* wq_tpt = (ushort*)alloc((size_t)1024 * 1024 * 2);
    ushort* wb_out = (ushort*)alloc((size_t)1024 * 4096 * 2);
    ushort* tfq_bf  = (ushort*)alloc((size_t)128 * 1024 * 2);
    ushort* iofq_bf = (ushort*)alloc((size_t)128 * 1024 * 2);
    ushort* ipfq_bf = (ushort*)alloc((size_t)128 * 1024 * 2);
    uchar* w8_t2o = (uchar*)alloc((size_t)1024 * 1024);
    uchar* w8_t2p = (uchar*)alloc((size_t)1024 * 1024);
    uchar* w8_o2t = (uchar*)alloc((size_t)1024 * 1024);
    uchar* w8_p2t = (uchar*)alloc((size_t)1024 * 1024);
    uchar* tf8  = (uchar*)alloc((size_t)32768 * 1024);
    uchar* iof8 = (uchar*)alloc((size_t)8192 * 1024);
    uchar* ipf8 = (uchar*)alloc((size_t)8192 * 1024);
    // q buffers + scores CONTIGUOUS (single memset covers them)
    float* q_tot = (float*)alloc((size_t)128 * 1024 * 4);
    float* q_tpt = (float*)alloc((size_t)128 * 1024 * 4);
    float* q_oo  = (float*)alloc((size_t)128 * 1024 * 4);
    float* q_pp  = (float*)alloc((size_t)128 * 1024 * 4);
    float* scores = (float*)alloc((size_t)(8192 * 2 + 32768 * 2) * 4);
    float* sc_io = scores, *sc_ip = scores + 8192, *sc_to = scores + 16384, *sc_tp = scores + 49152;
    ushort* comb_bf = (ushort*)alloc((size_t)128 * 4096 * 2);

    // ---- 1) fused conversions ----
    Cvt8Tab t8;
    const float* s8[7] = { W_t2o, W_t2p, W_o2t, W_p2t, text_feats, img_object_feats, img_place_feats };
    uchar* d8[7] = { w8_t2o, w8_t2p, w8_o2t, w8_p2t, tf8, iof8, ipf8 };
    unsigned n16[7] = { 65536, 65536, 65536, 65536, 2097152, 524288, 524288 };
    unsigned cum8 = 0;
    for (int i = 0; i < 7; ++i) { t8.src[i] = s8[i]; t8.dst[i] = d8[i]; t8.cum[i] = cum8; cum8 += n16[i]; }
    t8.src[7] = nullptr; t8.dst[7] = nullptr; t8.cum[7] = cum8; t8.cum[8] = cum8;

    CvtTab tb;
    const float* sb[8] = { W_oo, W_pp, W_tot, W_tpt, W_out, text_feat, img_object_feat, img_place_feat };
    ushort* db[8] = { wq_oo, wq_pp, wq_tot, wq_tpt, wb_out, tfq_bf, iofq_bf, ipfq_bf };
    unsigned nb4[8] = { 262144, 262144, 262144, 262144, 1048576, 32768, 32768, 32768 };
    unsigned cumb = 0;
    for (int i = 0; i < 8; ++i) { tb.src[i] = sb[i]; tb.dst[i] = db[i]; tb.cum[i] = cumb; cumb += nb4[i]; }
    tb.cum[8] = cumb;
    cvt_all<<<4096, 256, 0, stream>>>(t8, cum8, tb, cumb);

    // ---- 2) zero atomic targets (q buffers + scores contiguous; d_out) ----
    hipMemsetAsync(q_tot, 0, (size_t)4 * 524288 + 327680, stream);
    hipMemsetAsync(d_out, 0, (size_t)128 * 1024 * 4, stream);

    // ---- 3) fused q projections (bf16, split-K z=4) ----
    QArgs qa;
    qa.A[0] = tfq_bf;  qa.W[0] = wq_tot; qa.bias[0] = b_tot; qa.out[0] = q_tot;
    qa.A[1] = tfq_bf;  qa.W[1] = wq_tpt; qa.bias[1] = b_tpt; qa.out[1] = q_tpt;
    qa.A[2] = iofq_bf; qa.W[2] = wq_oo;  qa.bias[2] = b_oo;  qa.out[2] = q_oo;
    qa.A[3] = ipfq_bf; qa.W[3] = wq_pp;  qa.bias[3] = b_pp;  qa.out[3] = q_pp;
    gemm_q<<<dim3(4, 8, 4), 256, 0, stream>>>(qa, 256);

    // ---- 4) score GEMMs (fp8 packed-pair, BK=64, 64KB dbuf) ----
    PArgs pi;
    pi.A[0] = iof8;   pi.Wa[0] = w8_o2t; pi.Wb[0] = w8_o2t;
    pi.qa[0] = q_tot; pi.qb[0] = q_tot;  pi.va[0] = v_to; pi.vb[0] = v_to;
    pi.oa[0] = sc_io; pi.ob[0] = sc_io;
    pi.A[1] = ipf8;   pi.Wa[1] = w8_p2t; pi.Wb[1] = w8_p2t;
    pi.qa[1] = q_tpt; pi.qb[1] = q_tpt;  pi.va[1] = v_tp; pi.vb[1] = v_tp;
    pi.oa[1] = sc_ip; pi.ob[1] = sc_ip;
    gemm_pipe8<<<dim3(64, 4), 512, 65536, stream>>>(pi, 256, 128, 6, 5);

    PArgs pt;
    pt.A[0] = tf8;    pt.Wa[0] = w8_t2o; pt.Wb[0] = w8_t2p;
    pt.qa[0] = q_oo;  pt.qb[0] = q_pp;   pt.va[0] = v_io; pt.vb[0] = v_ip;
    pt.oa[0] = sc_to; pt.ob[0] = sc_tp;
    pt.A[1] = pt.A[0]; pt.Wa[1] = pt.Wa[0]; pt.Wb[1] = pt.Wb[0];
    pt.qa[1] = pt.qa[0]; pt.qb[1] = pt.qb[0]; pt.va[1] = pt.va[0]; pt.vb[1] = pt.vb[0];
    pt.oa[1] = pt.oa[0]; pt.ob[1] = pt.ob[0];
    gemm_pipe8<<<dim3(128, 8), 512, 65536, stream>>>(pt, 128, 0, 8, 7);

    // ---- 5) fused softmax + context -> combined (bf16) ----
    softmax_ctx<<<dim3(128, 4), 256, 0, stream>>>(
        text_feats, img_object_feats, img_place_feats,
        sc_to, sc_tp, sc_io, sc_ip, src_mask, comb_bf);

    // ---- 6) out = combined @ W_out^T + b_out (split-K=16, atomic) ----
    gemm_fin<<<dim3(1, 8, 16), 256, 0, stream>>>(comb_bf, wb_out, b_out, (float*)d_out, 4096, 256);
}

// Round 15
// 270.057 us; speedup vs baseline: 1.1243x; 1.0161x over previous
//
#include <hip/hip_runtime.h>
#include <hip/hip_bf16.h>

typedef __attribute__((ext_vector_type(8))) short bf16x8;
typedef __attribute__((ext_vector_type(4))) float f32x4;
typedef __attribute__((ext_vector_type(2))) long lx2;

__device__ __forceinline__ uint pack_bf16x2(float a, float b) {
    __hip_bfloat162 p = __float22bfloat162_rn(make_float2(a, b));
    union { __hip_bfloat162 h; uint u; } c; c.h = p; return c.u;
}

__device__ __forceinline__ float fast_tanh(float x) {
    float e = __expf(2.f * x);
    return 1.f - 2.f * __builtin_amdgcn_rcpf(e + 1.f);
}

__device__ __forceinline__ float wredmax(float v) {
    #pragma unroll
    for (int o = 32; o; o >>= 1) v = fmaxf(v, __shfl_xor(v, o, 64));
    return v;
}
__device__ __forceinline__ float wredsum(float v) {
    #pragma unroll
    for (int o = 32; o; o >>= 1) v += __shfl_xor(v, o, 64);
    return v;
}

__device__ __forceinline__ void gload16(const void* g, void* l) {
    __builtin_amdgcn_global_load_lds(
        (const __attribute__((address_space(1))) void*)g,
        (__attribute__((address_space(3))) void*)l, 16, 0, 0);
}

// ---------------- fused batched conversion: f32->fp8 packed-pair + f32->bf16 ----------------
struct Cvt8Tab {
    const float* src[8];
    uchar* dst[8];
    unsigned cum[9];   // cumulative 16-byte output chunks
};
struct CvtTab {
    const float* src[8];
    ushort* dst[8];
    unsigned cum[9];   // cumulative float4 chunks
};

__device__ __forceinline__ uint pk8(float4 v) {
    int r = __builtin_amdgcn_cvt_pk_fp8_f32(v.x, v.y, 0, false);
    r = __builtin_amdgcn_cvt_pk_fp8_f32(v.z, v.w, r, true);
    return (uint)r;
}

__global__ void cvt_all(Cvt8Tab t8, unsigned total8, CvtTab tb, unsigned totalb) {
    unsigned stride = gridDim.x * blockDim.x;
    unsigned total = total8 + totalb;
    for (unsigned i = blockIdx.x * blockDim.x + threadIdx.x; i < total; i += stride) {
        if (i < total8) {
            int j = 0;
            while (i >= t8.cum[j + 1]) ++j;
            unsigned o = i - t8.cum[j];
            unsigned row = o >> 6, c = o & 63, tt = c >> 2, pp = c & 3;
            const float* s0 = t8.src[j] + (size_t)row * 1024 + tt * 64 + pp * 8;
            float4 a0 = *(const float4*)(s0);
            float4 a1 = *(const float4*)(s0 + 4);
            float4 b0 = *(const float4*)(s0 + 32);
            float4 b1 = *(const float4*)(s0 + 36);
            uint4 ov;
            ov.x = pk8(a0); ov.y = pk8(a1); ov.z = pk8(b0); ov.w = pk8(b1);
            *reinterpret_cast<uint4*>(t8.dst[j] + (size_t)o * 16) = ov;
        } else {
            unsigned ii = i - total8;
            int j = 0;
            while (ii >= tb.cum[j + 1]) ++j;
            unsigned off = ii - tb.cum[j];
            float4 v = reinterpret_cast<const float4*>(tb.src[j])[off];
            uint2 o;
            o.x = pack_bf16x2(v.x, v.y);
            o.y = pack_bf16x2(v.z, v.w);
            reinterpret_cast<uint2*>(tb.dst[j])[off] = o;
        }
    }
}

// ======== merged fp8 score GEMM: img (blocks 0..255) + text (blocks 256..1279) ========
// R12 core: 512 thr, 256x256 tile, BK=64, dbuf 64KB; packed-pair fp8 ->
// measured-zero-conflict b128 LDS reads; burst stage at tile top, one
// vmcnt(0)+barrier per tile. Merging the two dispatches overlaps the img tail
// with the text ramp and removes one launch gap; math identical to R14.
struct PArgs {
    const uchar* A[2];
    const uchar* Wa[2];
    const uchar* Wb[2];
    const float* qa[2];
    const float* qb[2];
    const float* va[2];
    const float* vb[2];
    float* oa[2];
    float* ob[2];
};

__global__ __launch_bounds__(512, 1) void gemm_pipe8(PArgs Pi, PArgs Pt)
{
    extern __shared__ char smem[];   // buf d: A @ d*32768 (16KB), W @ +16384 (16KB)

    const int tid = threadIdx.x;
    const int lane = tid & 63, wv = tid >> 6;
    const int wr = wv >> 2, wc = wv & 3;
    const int lrow = lane & 15, lk = lane >> 4;

    // ---- decode: img grid was (64,4) brshift=5; text grid was (128,8) brshift=7 ----
    int id = blockIdx.x;
    const PArgs* P;
    int x, y, nmul, nbadd, bshift, brshift;
    if (id < 256) {
        P = &Pi; x = id & 63; y = id >> 6;
        nmul = 256; nbadd = 128; bshift = 6; brshift = 5;
    } else {
        P = &Pt; id -= 256; x = id & 127; y = id >> 7;
        nmul = 128; nbadd = 0; bshift = 8; brshift = 7;
    }
    const int br = x >> brshift;
    const int m0 = (x & ((1 << brshift) - 1)) << 8;
    const int na = y * nmul;
    const int nb = na + nbadd;

    const uchar* A  = P->A[br];
    const uchar* Wa = P->Wa[br];
    const uchar* Wb = P->Wb[br];

    // staging map: thread t -> row r = u*128 + (t>>2), 16B slot s=(t&3);
    // stored slot s holds packed chunk c = s ^ ((r>>1)&3) = (t&3) ^ ((t>>3)&3).
    const int rr = tid >> 2;
    const int c  = (tid & 3) ^ ((tid >> 3) & 3);
    const uchar* sA0 = A  + (size_t)(m0 + rr) * 1024 + c * 16;
    const uchar* sA1 = A  + (size_t)(m0 + 128 + rr) * 1024 + c * 16;
    const uchar* sW0 = Wa + (size_t)(na + rr) * 1024 + c * 16;
    const uchar* sW1 = Wb + (size_t)(nb + rr) * 1024 + c * 16;

    auto stage = [&](int t, int d) {
        char* b = smem + d * 32768 + tid * 16;
        size_t k = (size_t)t * 64;
        gload16(sA0 + k, b);
        gload16(sA1 + k, b + 8192);
        gload16(sW0 + k, b + 16384);
        gload16(sW1 + k, b + 24576);
    };

    auto rdA = [&](int d, int mi) -> lx2 {
        int row = wr * 128 + mi * 16 + lrow;
        return *(const lx2*)(smem + d * 32768 + row * 64 +
                             ((lk ^ ((row >> 1) & 3)) << 4));
    };
    auto rdB = [&](int d, int ni) -> lx2 {
        int row = wc * 64 + ni * 16 + lrow;
        return *(const lx2*)(smem + d * 32768 + 16384 + row * 64 +
                             ((lk ^ ((row >> 1) & 3)) << 4));
    };

    f32x4 acc[8][4];
    #pragma unroll
    for (int i = 0; i < 8; ++i)
        #pragma unroll
        for (int j = 0; j < 4; ++j) { f32x4 z = {0.f,0.f,0.f,0.f}; acc[i][j] = z; }

    // prologue: stage tile 0
    stage(0, 0);
    asm volatile("s_waitcnt vmcnt(0)" ::: "memory");
    __syncthreads();

    auto body = [&](int t, int cur, int nxt, bool pf) {
        lx2 af[4], bfr[4];
        if (pf) stage(t + 1, nxt);   // burst-issue next tile's staging
        #pragma unroll
        for (int ni = 0; ni < 4; ++ni) bfr[ni] = rdB(cur, ni);
        #pragma unroll
        for (int mi = 0; mi < 4; ++mi) af[mi] = rdA(cur, mi);
        __builtin_amdgcn_s_setprio(1);
        #pragma unroll
        for (int mi = 0; mi < 4; ++mi)
            #pragma unroll
            for (int ni = 0; ni < 4; ++ni) {
                acc[mi][ni] = __builtin_amdgcn_mfma_f32_16x16x32_fp8_fp8(af[mi][0], bfr[ni][0], acc[mi][ni], 0, 0, 0);
                acc[mi][ni] = __builtin_amdgcn_mfma_f32_16x16x32_fp8_fp8(af[mi][1], bfr[ni][1], acc[mi][ni], 0, 0, 0);
            }
        __builtin_amdgcn_s_setprio(0);
        #pragma unroll
        for (int mi = 0; mi < 4; ++mi) af[mi] = rdA(cur, mi + 4);
        __builtin_amdgcn_s_setprio(1);
        #pragma unroll
        for (int mi = 0; mi < 4; ++mi)
            #pragma unroll
            for (int ni = 0; ni < 4; ++ni) {
                acc[mi + 4][ni] = __builtin_amdgcn_mfma_f32_16x16x32_fp8_fp8(af[mi][0], bfr[ni][0], acc[mi + 4][ni], 0, 0, 0);
                acc[mi + 4][ni] = __builtin_amdgcn_mfma_f32_16x16x32_fp8_fp8(af[mi][1], bfr[ni][1], acc[mi + 4][ni], 0, 0, 0);
            }
        __builtin_amdgcn_s_setprio(0);
        asm volatile("s_waitcnt vmcnt(0)" ::: "memory");
        __syncthreads();
    };

    #pragma unroll 1
    for (int tt = 0; tt < 8; ++tt) {
        body(2 * tt,     0, 1, true);
        body(2 * tt + 1, 1, 0, tt < 7);
    }

    // ---- score epilogue (per-wave side: wc<2 -> a, else -> b) ----
    const float* qsrc = (wc < 2) ? P->qa[br] : P->qb[br];
    const float* vsrc = (wc < 2) ? P->va[br] : P->vb[br];
    float* osrc       = (wc < 2) ? P->oa[br] : P->ob[br];
    const int nbase0 = ((wc < 2) ? na : nb) + (wc & 1) * 64;
    #pragma unroll
    for (int mi = 0; mi < 8; ++mi) {
        int mbase = m0 + wr * 128 + mi * 16;
        int bb = mbase >> bshift;
        const float* qrow = qsrc + (size_t)bb * 1024;
        float part[4] = {0.f, 0.f, 0.f, 0.f};
        #pragma unroll
        for (int ni = 0; ni < 4; ++ni) {
            int nn = nbase0 + ni * 16 + lrow;
            float qn = qrow[nn], vn = vsrc[nn];
            #pragma unroll
            for (int r2 = 0; r2 < 4; ++r2)
                part[r2] += fast_tanh(acc[mi][ni][r2] + qn) * vn;
        }
        #pragma unroll
        for (int off = 1; off < 16; off <<= 1)
            #pragma unroll
            for (int r2 = 0; r2 < 4; ++r2)
                part[r2] += __shfl_xor(part[r2], off, 64);
        if (lrow == 0) {
            #pragma unroll
            for (int r2 = 0; r2 < 4; ++r2)
                atomicAdd(&osrc[mbase + lk * 4 + r2], part[r2]);
        }
    }
}

// ============ fused 4-way q-projection, split-K z=4 (atomic): q += x @ W^T (+b at z0) ============
struct QArgs {
    const ushort* A[4];
    const ushort* W[4];
    const float* bias[4];
    float* out[4];
};

__global__ __launch_bounds__(256, 2) void gemm_q(QArgs Q, int kchunk)
{
    __shared__ char smemq[32768];
    char* As = smemq;
    char* Ws = smemq + 16384;

    const int tid = threadIdx.x;
    const int lane = tid & 63, wv = tid >> 6, wr = wv >> 1, wc = wv & 1;
    const int lrow = lane & 15, lk = lane >> 4;
    const int n0 = blockIdx.y << 7;
    const int nkt = kchunk >> 6;
    const int ktbase = blockIdx.z * nkt;

    const ushort* A = Q.A[blockIdx.x];
    const ushort* W = Q.W[blockIdx.x];

    f32x4 acc[4][4];
    #pragma unroll
    for (int i = 0; i < 4; ++i)
        #pragma unroll
        for (int j = 0; j < 4; ++j) { f32x4 z = {0.f,0.f,0.f,0.f}; acc[i][j] = z; }

    const int srow = tid >> 3;
    const int g = (tid & 7) ^ (srow & 7);
    const ushort* pA = A + (size_t)srow * 1024 + (size_t)ktbase * 64 + g * 8;
    const ushort* pW = W + (size_t)(n0 + srow) * 1024 + (size_t)ktbase * 64 + g * 8;

    for (int t = 0; t < nkt; ++t) {
        #pragma unroll
        for (int j = 0; j < 4; ++j)
            gload16(pA + (size_t)j * 32768 + (size_t)t * 64, As + j * 4096 + tid * 16);
        #pragma unroll
        for (int j = 0; j < 4; ++j)
            gload16(pW + (size_t)j * 32768 + (size_t)t * 64, Ws + j * 4096 + tid * 16);
        __syncthreads();
        #pragma unroll
        for (int ks = 0; ks < 2; ++ks) {
            bf16x8 af[4], bfr[4];
            const int q = ks * 4 + lk;
            #pragma unroll
            for (int mi = 0; mi < 4; ++mi) {
                int row = wr * 64 + mi * 16 + lrow;
                af[mi] = *(const bf16x8*)(As + row * 128 + ((q ^ (row & 7)) << 4));
            }
            #pragma unroll
            for (int ni = 0; ni < 4; ++ni) {
                int row = wc * 64 + ni * 16 + lrow;
                bfr[ni] = *(const bf16x8*)(Ws + row * 128 + ((q ^ (row & 7)) << 4));
            }
            #pragma unroll
            for (int mi = 0; mi < 4; ++mi)
                #pragma unroll
                for (int ni = 0; ni < 4; ++ni)
                    acc[mi][ni] = __builtin_amdgcn_mfma_f32_16x16x32_bf16(af[mi], bfr[ni], acc[mi][ni], 0, 0, 0);
        }
        __syncthreads();
    }

    float* out = Q.out[blockIdx.x];
    const float* bias = Q.bias[blockIdx.x];
    #pragma unroll
    for (int mi = 0; mi < 4; ++mi) {
        int mrow0 = wr * 64 + mi * 16 + lk * 4;
        #pragma unroll
        for (int ni = 0; ni < 4; ++ni) {
            int n = n0 + wc * 64 + ni * 16 + lrow;
            float bv = (blockIdx.z == 0) ? bias[n] : 0.f;
            #pragma unroll
            for (int r = 0; r < 4; ++r)
                atomicAdd(&out[(size_t)(mrow0 + r) * 1024 + n], acc[mi][ni][r] + bv);
        }
    }
}

// ============ final GEMM (split-K z=16, atomic, bf16) ============
__global__ __launch_bounds__(256, 2) void gemm_fin(
    const ushort* A, const ushort* W, const float* bias, float* out, int K, int kchunk)
{
    __shared__ char smemf[32768];
    char* As = smemf;
    char* Ws = smemf + 16384;

    const int tid = threadIdx.x;
    const int lane = tid & 63, wv = tid >> 6, wr = wv >> 1, wc = wv & 1;
    const int lrow = lane & 15, lk = lane >> 4;
    const int n0 = blockIdx.y << 7;
    const int nkt = kchunk >> 6;
    const int ktbase = blockIdx.z * nkt;

    f32x4 acc[4][4];
    #pragma unroll
    for (int i = 0; i < 4; ++i)
        #pragma unroll
        for (int j = 0; j < 4; ++j) { f32x4 z = {0.f,0.f,0.f,0.f}; acc[i][j] = z; }

    const int srow = tid >> 3;
    const int g = (tid & 7) ^ (srow & 7);
    const ushort* pA = A + (size_t)srow * K + ktbase * 64 + g * 8;
    const ushort* pW = W + (size_t)(n0 + srow) * K + ktbase * 64 + g * 8;

    for (int t = 0; t < nkt; ++t) {
        #pragma unroll
        for (int j = 0; j < 4; ++j)
            gload16(pA + (size_t)j * 32 * K + (size_t)t * 64, As + j * 4096 + tid * 16);
        #pragma unroll
        for (int j = 0; j < 4; ++j)
            gload16(pW + (size_t)j * 32 * K + (size_t)t * 64, Ws + j * 4096 + tid * 16);
        __syncthreads();
        #pragma unroll
        for (int ks = 0; ks < 2; ++ks) {
            bf16x8 af[4], bfr[4];
            const int q = ks * 4 + lk;
            #pragma unroll
            for (int mi = 0; mi < 4; ++mi) {
                int row = wr * 64 + mi * 16 + lrow;
                af[mi] = *(const bf16x8*)(As + row * 128 + ((q ^ (row & 7)) << 4));
            }
            #pragma unroll
            for (int ni = 0; ni < 4; ++ni) {
                int row = wc * 64 + ni * 16 + lrow;
                bfr[ni] = *(const bf16x8*)(Ws + row * 128 + ((q ^ (row & 7)) << 4));
            }
            #pragma unroll
            for (int mi = 0; mi < 4; ++mi)
                #pragma unroll
                for (int ni = 0; ni < 4; ++ni)
                    acc[mi][ni] = __builtin_amdgcn_mfma_f32_16x16x32_bf16(af[mi], bfr[ni], acc[mi][ni], 0, 0, 0);
        }
        __syncthreads();
    }

    #pragma unroll
    for (int mi = 0; mi < 4; ++mi) {
        int mrow0 = wr * 64 + mi * 16 + lk * 4;
        #pragma unroll
        for (int ni = 0; ni < 4; ++ni) {
            int n = n0 + wc * 64 + ni * 16 + lrow;
            float bv = (blockIdx.z == 0) ? bias[n] : 0.f;
            #pragma unroll
            for (int r = 0; r < 4; ++r)
                atomicAdd(&out[(size_t)(mrow0 + r) * 1024 + n], acc[mi][ni][r] + bv);
        }
    }
}

// ---- fused softmax + context: y<2 = text d-halves, y>=2 = img branches (f32 feats) ----
__global__ void softmax_ctx(const float* __restrict__ tf,
                            const float* __restrict__ iof, const float* __restrict__ ipf,
                            const float* __restrict__ sc_to, const float* __restrict__ sc_tp,
                            const float* __restrict__ sc_io, const float* __restrict__ sc_ip,
                            const float* __restrict__ mask, ushort* __restrict__ combined)
{
    int b = blockIdx.x, y = blockIdx.y;
    int tid = threadIdx.x, lane = tid & 63, wv = tid >> 6;
    if (y >= 2) {
        int brn = y - 2;
        const float* A  = brn ? ipf : iof;
        const float* sc = brn ? sc_ip : sc_io;
        __shared__ float dist[64];
        if (tid < 64) {
            float s  = sc[b * 64 + tid];
            float mx = wredmax(s);
            float e  = __expf(s - mx);
            float sm = wredsum(e);
            dist[tid] = e / sm;
        }
        __syncthreads();
        int d0 = tid * 4;
        float a0 = 0, a1 = 0, a2 = 0, a3 = 0;
        const float* base = A + (size_t)b * 64 * 1024 + d0;
        #pragma unroll 4
        for (int n = 0; n < 64; ++n) {
            float w = dist[n];
            float4 t = *(const float4*)(base + (size_t)n * 1024);
            a0 += w * t.x; a1 += w * t.y; a2 += w * t.z; a3 += w * t.w;
        }
        uint2 o;
        o.x = pack_bf16x2(a0, a1);
        o.y = pack_bf16x2(a2, a3);
        *(uint2*)(combined + (size_t)b * 4096 + brn * 1024 + d0) = o;
    } else {
        __shared__ float d3[256], d4[256], red[8];
        float s3 = sc_to[b * 256 + tid], s4 = sc_tp[b * 256 + tid], m = mask[b * 256 + tid];
        float m3 = wredmax(s3), m4 = wredmax(s4);
        if (lane == 0) { red[wv] = m3; red[4 + wv] = m4; }
        __syncthreads();
        m3 = fmaxf(fmaxf(red[0], red[1]), fmaxf(red[2], red[3]));
        m4 = fmaxf(fmaxf(red[4], red[5]), fmaxf(red[6], red[7]));
        float e3 = __expf(s3 - m3) * m, e4 = __expf(s4 - m4) * m;
        float t3 = wredsum(e3), t4 = wredsum(e4);
        __syncthreads();
        if (lane == 0) { red[wv] = t3; red[4 + wv] = t4; }
        __syncthreads();
        t3 = red[0] + red[1] + red[2] + red[3];
        t4 = red[4] + red[5] + red[6] + red[7];
        d3[tid] = e3 / t3; d4[tid] = e4 / t4;
        __syncthreads();
        int d0 = y * 512 + tid * 2;
        float a0 = 0, a1 = 0, c0 = 0, c1 = 0;
        const float* base = tf + (size_t)b * 256 * 1024 + d0;
        #pragma unroll 4
        for (int l = 0; l < 256; ++l) {
            float w3 = d3[l], w4 = d4[l];
            float2 t = *(const float2*)(base + (size_t)l * 1024);
            a0 += w3 * t.x; a1 += w3 * t.y;
            c0 += w4 * t.x; c1 += w4 * t.y;
        }
        *(uint*)(combined + (size_t)b * 4096 + 2048 + d0) = pack_bf16x2(a0, a1);
        *(uint*)(combined + (size_t)b * 4096 + 3072 + d0) = pack_bf16x2(c0, c1);
    }
}

extern "C" void kernel_launch(void* const* d_in, const int* in_sizes, int n_in,
                              void* d_out, int out_size, void* d_ws, size_t ws_size,
                              hipStream_t stream) {
    const float* text_feat        = (const float*)d_in[0];
    const float* text_feats       = (const float*)d_in[1];
    const float* img_object_feat  = (const float*)d_in[2];
    const float* img_object_feats = (const float*)d_in[3];
    const float* img_place_feat   = (const float*)d_in[4];
    const float* img_place_feats  = (const float*)d_in[5];
    const float* src_mask         = (const float*)d_in[6];
    const float* v_to  = (const float*)d_in[7];
    const float* v_tp  = (const float*)d_in[8];
    const float* v_io  = (const float*)d_in[9];
    const float* v_ip  = (const float*)d_in[10];
    const float* W_t2o = (const float*)d_in[11];
    const float* W_t2p = (const float*)d_in[12];
    const float* W_o2t = (const float*)d_in[13];
    const float* W_p2t = (const float*)d_in[14];
    const float* W_oo  = (const float*)d_in[15];
    const float* b_oo  = (const float*)d_in[16];
    const float* W_pp  = (const float*)d_in[17];
    const float* b_pp  = (const float*)d_in[18];
    const float* W_tot = (const float*)d_in[19];
    const float* b_tot = (const float*)d_in[20];
    const float* W_tpt = (const float*)d_in[21];
    const float* b_tpt = (const float*)d_in[22];
    const float* W_out = (const float*)d_in[23];
    const float* b_out = (const float*)d_in[24];

    // ---- workspace layout ----
    char* p = (char*)d_ws;
    auto alloc = [&](size_t bytes) { char* r = p; p += (bytes + 255) & ~(size_t)255; return r; };
    ushort* wq_oo  = (ushort*)alloc((size_t)1024 * 1024 * 2);
    ushort* wq_pp  = (ushort*)alloc((size_t)1024 * 1024 * 2);
    ushort* wq_tot = (ushort*)alloc((size_t)1024 * 1024 * 2);
    ushort* wq_tpt = (ushort*)alloc((size_t)1024 * 1024 * 2);
    ushort* wb_out = (ushort*)alloc((size_t)1024 * 4096 * 2);
    ushort* tfq_bf  = (ushort*)alloc((size_t)128 * 1024 * 2);
    ushort* iofq_bf = (ushort*)alloc((size_t)128 * 1024 * 2);
    ushort* ipfq_bf = (ushort*)alloc((size_t)128 * 1024 * 2);
    uchar* w8_t2o = (uchar*)alloc((size_t)1024 * 1024);
    uchar* w8_t2p = (uchar*)alloc((size_t)1024 * 1024);
    uchar* w8_o2t = (uchar*)alloc((size_t)1024 * 1024);
    uchar* w8_p2t = (uchar*)alloc((size_t)1024 * 1024);
    uchar* tf8  = (uchar*)alloc((size_t)32768 * 1024);
    uchar* iof8 = (uchar*)alloc((size_t)8192 * 1024);
    uchar* ipf8 = (uchar*)alloc((size_t)8192 * 1024);
    // q buffers + scores CONTIGUOUS (single memset covers them)
    float* q_tot = (float*)alloc((size_t)128 * 1024 * 4);
    float* q_tpt = (float*)alloc((size_t)128 * 1024 * 4);
    float* q_oo  = (float*)alloc((size_t)128 * 1024 * 4);
    float* q_pp  = (float*)alloc((size_t)128 * 1024 * 4);
    float* scores = (float*)alloc((size_t)(8192 * 2 + 32768 * 2) * 4);
    float* sc_io = scores, *sc_ip = scores + 8192, *sc_to = scores + 16384, *sc_tp = scores + 49152;
    ushort* comb_bf = (ushort*)alloc((size_t)128 * 4096 * 2);

    // ---- 1) fused conversions ----
    Cvt8Tab t8;
    const float* s8[7] = { W_t2o, W_t2p, W_o2t, W_p2t, text_feats, img_object_feats, img_place_feats };
    uchar* d8[7] = { w8_t2o, w8_t2p, w8_o2t, w8_p2t, tf8, iof8, ipf8 };
    unsigned n16[7] = { 65536, 65536, 65536, 65536, 2097152, 524288, 524288 };
    unsigned cum8 = 0;
    for (int i = 0; i < 7; ++i) { t8.src[i] = s8[i]; t8.dst[i] = d8[i]; t8.cum[i] = cum8; cum8 += n16[i]; }
    t8.src[7] = nullptr; t8.dst[7] = nullptr; t8.cum[7] = cum8; t8.cum[8] = cum8;

    CvtTab tb;
    const float* sb[8] = { W_oo, W_pp, W_tot, W_tpt, W_out, text_feat, img_object_feat, img_place_feat };
    ushort* db[8] = { wq_oo, wq_pp, wq_tot, wq_tpt, wb_out, tfq_bf, iofq_bf, ipfq_bf };
    unsigned nb4[8] = { 262144, 262144, 262144, 262144, 1048576, 32768, 32768, 32768 };
    unsigned cumb = 0;
    for (int i = 0; i < 8; ++i) { tb.src[i] = sb[i]; tb.dst[i] = db[i]; tb.cum[i] = cumb; cumb += nb4[i]; }
    tb.cum[8] = cumb;
    cvt_all<<<4096, 256, 0, stream>>>(t8, cum8, tb, cumb);

    // ---- 2) zero atomic targets (q buffers + scores contiguous; d_out) ----
    hipMemsetAsync(q_tot, 0, (size_t)4 * 524288 + 327680, stream);
    hipMemsetAsync(d_out, 0, (size_t)128 * 1024 * 4, stream);

    // ---- 3) fused q projections (bf16, split-K z=4) ----
    QArgs qa;
    qa.A[0] = tfq_bf;  qa.W[0] = wq_tot; qa.bias[0] = b_tot; qa.out[0] = q_tot;
    qa.A[1] = tfq_bf;  qa.W[1] = wq_tpt; qa.bias[1] = b_tpt; qa.out[1] = q_tpt;
    qa.A[2] = iofq_bf; qa.W[2] = wq_oo;  qa.bias[2] = b_oo;  qa.out[2] = q_oo;
    qa.A[3] = ipfq_bf; qa.W[3] = wq_pp;  qa.bias[3] = b_pp;  qa.out[3] = q_pp;
    gemm_q<<<dim3(4, 8, 4), 256, 0, stream>>>(qa, 256);

    // ---- 4) merged score GEMMs (fp8 packed-pair, BK=64, 64KB dbuf; 1280 blocks) ----
    PArgs pi;
    pi.A[0] = iof8;   pi.Wa[0] = w8_o2t; pi.Wb[0] = w8_o2t;
    pi.qa[0] = q_tot; pi.qb[0] = q_tot;  pi.va[0] = v_to; pi.vb[0] = v_to;
    pi.oa[0] = sc_io; pi.ob[0] = sc_io;
    pi.A[1] = ipf8;   pi.Wa[1] = w8_p2t; pi.Wb[1] = w8_p2t;
    pi.qa[1] = q_tpt; pi.qb[1] = q_tpt;  pi.va[1] = v_tp; pi.vb[1] = v_tp;
    pi.oa[1] = sc_ip; pi.ob[1] = sc_ip;

    PArgs pt;
    pt.A[0] = tf8;    pt.Wa[0] = w8_t2o; pt.Wb[0] = w8_t2p;
    pt.qa[0] = q_oo;  pt.qb[0] = q_pp;   pt.va[0] = v_io; pt.vb[0] = v_ip;
    pt.oa[0] = sc_to; pt.ob[0] = sc_tp;
    pt.A[1] = pt.A[0]; pt.Wa[1] = pt.Wa[0]; pt.Wb[1] = pt.Wb[0];
    pt.qa[1] = pt.qa[0]; pt.qb[1] = pt.qb[0]; pt.va[1] = pt.va[0]; pt.vb[1] = pt.vb[0];
    pt.oa[1] = pt.oa[0]; pt.ob[1] = pt.ob[0];

    gemm_pipe8<<<dim3(1280), 512, 65536, stream>>>(pi, pt);

    // ---- 5) fused softmax + context -> combined (bf16) ----
    softmax_ctx<<<dim3(128, 4), 256, 0, stream>>>(
        text_feats, img_object_feats, img_place_feats,
        sc_to, sc_tp, sc_io, sc_ip, src_mask, comb_bf);

    // ---- 6) out = combined @ W_out^T + b_out (split-K=16, atomic) ----
    gemm_fin<<<dim3(1, 8, 16), 256, 0, stream>>>(comb_bf, wb_out, b_out, (float*)d_out, 4096, 256);
}

// Round 16
// 246.720 us; speedup vs baseline: 1.2307x; 1.0946x over previous
//
#include <hip/hip_runtime.h>
#include <hip/hip_bf16.h>

typedef __attribute__((ext_vector_type(8))) short bf16x8;
typedef __attribute__((ext_vector_type(4))) float f32x4;
typedef __attribute__((ext_vector_type(2))) long lx2;

__device__ __forceinline__ uint pack_bf16x2(float a, float b) {
    __hip_bfloat162 p = __float22bfloat162_rn(make_float2(a, b));
    union { __hip_bfloat162 h; uint u; } c; c.h = p; return c.u;
}

__device__ __forceinline__ float fast_tanh(float x) {
    float e = __expf(2.f * x);
    return 1.f - 2.f * __builtin_amdgcn_rcpf(e + 1.f);
}

__device__ __forceinline__ float wredmax(float v) {
    #pragma unroll
    for (int o = 32; o; o >>= 1) v = fmaxf(v, __shfl_xor(v, o, 64));
    return v;
}
__device__ __forceinline__ float wredsum(float v) {
    #pragma unroll
    for (int o = 32; o; o >>= 1) v += __shfl_xor(v, o, 64);
    return v;
}

__device__ __forceinline__ void gload16(const void* g, void* l) {
    __builtin_amdgcn_global_load_lds(
        (const __attribute__((address_space(1))) void*)g,
        (__attribute__((address_space(3))) void*)l, 16, 0, 0);
}

// ---- fused conversion (f32->fp8 packed-pair + f32->bf16) + zero-fill of atomic targets ----
struct Cvt8Tab {
    const float* src[8];
    uchar* dst[8];
    unsigned cum[9];   // cumulative 16-byte output chunks
};
struct CvtTab {
    const float* src[8];
    ushort* dst[8];
    unsigned cum[9];   // cumulative float4 chunks
};

__device__ __forceinline__ uint pk8(float4 v) {
    int r = __builtin_amdgcn_cvt_pk_fp8_f32(v.x, v.y, 0, false);
    r = __builtin_amdgcn_cvt_pk_fp8_f32(v.z, v.w, r, true);
    return (uint)r;
}

__global__ void cvt_all(Cvt8Tab t8, unsigned total8, CvtTab tb, unsigned totalb,
                        uint4* z1, unsigned n1, uint4* z2, unsigned n2) {
    unsigned stride = gridDim.x * blockDim.x;
    unsigned total = total8 + totalb + n1 + n2;
    for (unsigned i = blockIdx.x * blockDim.x + threadIdx.x; i < total; i += stride) {
        if (i < total8) {
            int j = 0;
            while (i >= t8.cum[j + 1]) ++j;
            unsigned o = i - t8.cum[j];
            unsigned row = o >> 6, c = o & 63, tt = c >> 2, pp = c & 3;
            const float* s0 = t8.src[j] + (size_t)row * 1024 + tt * 64 + pp * 8;
            float4 a0 = *(const float4*)(s0);
            float4 a1 = *(const float4*)(s0 + 4);
            float4 b0 = *(const float4*)(s0 + 32);
            float4 b1 = *(const float4*)(s0 + 36);
            uint4 ov;
            ov.x = pk8(a0); ov.y = pk8(a1); ov.z = pk8(b0); ov.w = pk8(b1);
            *reinterpret_cast<uint4*>(t8.dst[j] + (size_t)o * 16) = ov;
        } else if (i < total8 + totalb) {
            unsigned ii = i - total8;
            int j = 0;
            while (ii >= tb.cum[j + 1]) ++j;
            unsigned off = ii - tb.cum[j];
            float4 v = reinterpret_cast<const float4*>(tb.src[j])[off];
            uint2 o;
            o.x = pack_bf16x2(v.x, v.y);
            o.y = pack_bf16x2(v.z, v.w);
            reinterpret_cast<uint2*>(tb.dst[j])[off] = o;
        } else {
            unsigned ii = i - total8 - totalb;
            uint4 zz = {0u, 0u, 0u, 0u};
            if (ii < n1) z1[ii] = zz;
            else z2[ii - n1] = zz;
        }
    }
}

// ======== merged fp8 score GEMM: 128x256 tile, 256 thr (4 waves), dbuf 48KB, 2 blk/CU ========
// TLP structure (R2-measured 13.1 B/cyc/CU): two independent blocks per CU mask each
// other's stage-drain (R6's spill trap avoided: acc 128 + operands ~190 VGPR fits the
// (256,2) 256-reg tier). Packed-pair fp8 + measured-zero-conflict b128 read swizzle
// unchanged. LDS buf d @ d*24576: A rows 0..127 @0 (8KB), W rows 0..255 @8192 (16KB).
// Blocks: img 0..511 (x=mt|br, 64mt, brshift6, y<4), text 512..2559 (256mt, y<8).
struct PArgs {
    const uchar* A[2];
    const uchar* Wa[2];
    const uchar* Wb[2];
    const float* qa[2];
    const float* qb[2];
    const float* va[2];
    const float* vb[2];
    float* oa[2];
    float* ob[2];
};

__global__ __launch_bounds__(256, 2) void gemm_pipe8(PArgs Pi, PArgs Pt)
{
    extern __shared__ char smem[];

    const int tid = threadIdx.x;
    const int lane = tid & 63, wv = tid >> 6;
    const int wr = wv >> 1, wc = wv & 1;
    const int lrow = lane & 15, lk = lane >> 4;

    int id = blockIdx.x;
    const PArgs* P;
    int x, y, nmul, nbadd, bshift, brshift;
    if (id < 512) {
        P = &Pi; x = id & 127; y = id >> 7;
        nmul = 256; nbadd = 128; bshift = 6; brshift = 6;
    } else {
        P = &Pt; id -= 512; x = id & 255; y = id >> 8;
        nmul = 128; nbadd = 0; bshift = 8; brshift = 8;
    }
    const int br = x >> brshift;
    const int m0 = (x & ((1 << brshift) - 1)) << 7;
    const int na = y * nmul;
    const int nb = na + nbadd;

    const uchar* A  = P->A[br];
    const uchar* Wa = P->Wa[br];
    const uchar* Wb = P->Wb[br];

    // staging: 6 gload16/thread; unit j covers 64 rows; thread t -> row rr=t>>2,
    // slot s=t&3 holding packed chunk c = s ^ ((rr>>1)&3)  (row+64 invariant).
    const int rr = tid >> 2;
    const int c  = (tid & 3) ^ ((tid >> 3) & 3);
    const uchar* sA0 = A  + (size_t)(m0 + rr) * 1024 + c * 16;
    const uchar* sA1 = A  + (size_t)(m0 + 64 + rr) * 1024 + c * 16;
    const uchar* sW0 = Wa + (size_t)(na + rr) * 1024 + c * 16;
    const uchar* sW1 = Wa + (size_t)(na + 64 + rr) * 1024 + c * 16;
    const uchar* sW2 = Wb + (size_t)(nb + rr) * 1024 + c * 16;
    const uchar* sW3 = Wb + (size_t)(nb + 64 + rr) * 1024 + c * 16;

    auto stage = [&](int t, int d) {
        char* b = smem + d * 24576 + tid * 16;
        size_t k = (size_t)t * 64;
        gload16(sA0 + k, b);
        gload16(sA1 + k, b + 4096);
        gload16(sW0 + k, b + 8192);
        gload16(sW1 + k, b + 12288);
        gload16(sW2 + k, b + 16384);
        gload16(sW3 + k, b + 20480);
    };

    auto rdA = [&](int d, int mi) -> lx2 {
        int row = wr * 64 + mi * 16 + lrow;
        return *(const lx2*)(smem + d * 24576 + row * 64 +
                             ((lk ^ ((row >> 1) & 3)) << 4));
    };
    auto rdB = [&](int d, int ni) -> lx2 {
        int row = wc * 128 + ni * 16 + lrow;
        return *(const lx2*)(smem + d * 24576 + 8192 + row * 64 +
                             ((lk ^ ((row >> 1) & 3)) << 4));
    };

    f32x4 acc[4][8];
    #pragma unroll
    for (int i = 0; i < 4; ++i)
        #pragma unroll
        for (int j = 0; j < 8; ++j) { f32x4 z = {0.f,0.f,0.f,0.f}; acc[i][j] = z; }

    // prologue: stage tile 0
    stage(0, 0);
    asm volatile("s_waitcnt vmcnt(0)" ::: "memory");
    __syncthreads();

    auto body = [&](int t, int cur, int nxt, bool pf) {
        lx2 af[4], bfr[4];
        if (pf) stage(t + 1, nxt);   // burst-issue next tile (other block computes meanwhile)
        #pragma unroll
        for (int mi = 0; mi < 4; ++mi) af[mi] = rdA(cur, mi);
        // ---- ni 0-3
        #pragma unroll
        for (int ni = 0; ni < 4; ++ni) bfr[ni] = rdB(cur, ni);
        __builtin_amdgcn_s_setprio(1);
        #pragma unroll
        for (int mi = 0; mi < 4; ++mi)
            #pragma unroll
            for (int ni = 0; ni < 4; ++ni) {
                acc[mi][ni] = __builtin_amdgcn_mfma_f32_16x16x32_fp8_fp8(af[mi][0], bfr[ni][0], acc[mi][ni], 0, 0, 0);
                acc[mi][ni] = __builtin_amdgcn_mfma_f32_16x16x32_fp8_fp8(af[mi][1], bfr[ni][1], acc[mi][ni], 0, 0, 0);
            }
        __builtin_amdgcn_s_setprio(0);
        // ---- ni 4-7
        #pragma unroll
        for (int ni = 0; ni < 4; ++ni) bfr[ni] = rdB(cur, ni + 4);
        __builtin_amdgcn_s_setprio(1);
        #pragma unroll
        for (int mi = 0; mi < 4; ++mi)
            #pragma unroll
            for (int ni = 0; ni < 4; ++ni) {
                acc[mi][ni + 4] = __builtin_amdgcn_mfma_f32_16x16x32_fp8_fp8(af[mi][0], bfr[ni][0], acc[mi][ni + 4], 0, 0, 0);
                acc[mi][ni + 4] = __builtin_amdgcn_mfma_f32_16x16x32_fp8_fp8(af[mi][1], bfr[ni][1], acc[mi][ni + 4], 0, 0, 0);
            }
        __builtin_amdgcn_s_setprio(0);
        asm volatile("s_waitcnt vmcnt(0)" ::: "memory");
        __syncthreads();
    };

    #pragma unroll 1
    for (int tt = 0; tt < 8; ++tt) {
        body(2 * tt,     0, 1, true);
        body(2 * tt + 1, 1, 0, tt < 7);
    }

    // ---- score epilogue (per-wave side = wc) ----
    const float* qsrc = wc ? P->qb[br] : P->qa[br];
    const float* vsrc = wc ? P->vb[br] : P->va[br];
    float* osrc       = wc ? P->ob[br] : P->oa[br];
    const int nbase = wc ? nb : na;
    #pragma unroll
    for (int mi = 0; mi < 4; ++mi) {
        int mbase = m0 + wr * 64 + mi * 16;
        int bb = mbase >> bshift;
        const float* qrow = qsrc + (size_t)bb * 1024;
        float part[4] = {0.f, 0.f, 0.f, 0.f};
        #pragma unroll
        for (int ni = 0; ni < 8; ++ni) {
            int nn = nbase + ni * 16 + lrow;
            float qn = qrow[nn], vn = vsrc[nn];
            #pragma unroll
            for (int r2 = 0; r2 < 4; ++r2)
                part[r2] += fast_tanh(acc[mi][ni][r2] + qn) * vn;
        }
        #pragma unroll
        for (int off = 1; off < 16; off <<= 1)
            #pragma unroll
            for (int r2 = 0; r2 < 4; ++r2)
                part[r2] += __shfl_xor(part[r2], off, 64);
        if (lrow == 0) {
            #pragma unroll
            for (int r2 = 0; r2 < 4; ++r2)
                atomicAdd(&osrc[mbase + lk * 4 + r2], part[r2]);
        }
    }
}

// ============ fused 4-way q-projection, split-K z=4 (atomic): q += x @ W^T (+b at z0) ============
struct QArgs {
    const ushort* A[4];
    const ushort* W[4];
    const float* bias[4];
    float* out[4];
};

__global__ __launch_bounds__(256, 2) void gemm_q(QArgs Q, int kchunk)
{
    __shared__ char smemq[32768];
    char* As = smemq;
    char* Ws = smemq + 16384;

    const int tid = threadIdx.x;
    const int lane = tid & 63, wv = tid >> 6, wr = wv >> 1, wc = wv & 1;
    const int lrow = lane & 15, lk = lane >> 4;
    const int n0 = blockIdx.y << 7;
    const int nkt = kchunk >> 6;
    const int ktbase = blockIdx.z * nkt;

    const ushort* A = Q.A[blockIdx.x];
    const ushort* W = Q.W[blockIdx.x];

    f32x4 acc[4][4];
    #pragma unroll
    for (int i = 0; i < 4; ++i)
        #pragma unroll
        for (int j = 0; j < 4; ++j) { f32x4 z = {0.f,0.f,0.f,0.f}; acc[i][j] = z; }

    const int srow = tid >> 3;
    const int g = (tid & 7) ^ (srow & 7);
    const ushort* pA = A + (size_t)srow * 1024 + (size_t)ktbase * 64 + g * 8;
    const ushort* pW = W + (size_t)(n0 + srow) * 1024 + (size_t)ktbase * 64 + g * 8;

    for (int t = 0; t < nkt; ++t) {
        #pragma unroll
        for (int j = 0; j < 4; ++j)
            gload16(pA + (size_t)j * 32768 + (size_t)t * 64, As + j * 4096 + tid * 16);
        #pragma unroll
        for (int j = 0; j < 4; ++j)
            gload16(pW + (size_t)j * 32768 + (size_t)t * 64, Ws + j * 4096 + tid * 16);
        __syncthreads();
        #pragma unroll
        for (int ks = 0; ks < 2; ++ks) {
            bf16x8 af[4], bfr[4];
            const int q = ks * 4 + lk;
            #pragma unroll
            for (int mi = 0; mi < 4; ++mi) {
                int row = wr * 64 + mi * 16 + lrow;
                af[mi] = *(const bf16x8*)(As + row * 128 + ((q ^ (row & 7)) << 4));
            }
            #pragma unroll
            for (int ni = 0; ni < 4; ++ni) {
                int row = wc * 64 + ni * 16 + lrow;
                bfr[ni] = *(const bf16x8*)(Ws + row * 128 + ((q ^ (row & 7)) << 4));
            }
            #pragma unroll
            for (int mi = 0; mi < 4; ++mi)
                #pragma unroll
                for (int ni = 0; ni < 4; ++ni)
                    acc[mi][ni] = __builtin_amdgcn_mfma_f32_16x16x32_bf16(af[mi], bfr[ni], acc[mi][ni], 0, 0, 0);
        }
        __syncthreads();
    }

    float* out = Q.out[blockIdx.x];
    const float* bias = Q.bias[blockIdx.x];
    #pragma unroll
    for (int mi = 0; mi < 4; ++mi) {
        int mrow0 = wr * 64 + mi * 16 + lk * 4;
        #pragma unroll
        for (int ni = 0; ni < 4; ++ni) {
            int n = n0 + wc * 64 + ni * 16 + lrow;
            float bv = (blockIdx.z == 0) ? bias[n] : 0.f;
            #pragma unroll
            for (int r = 0; r < 4; ++r)
                atomicAdd(&out[(size_t)(mrow0 + r) * 1024 + n], acc[mi][ni][r] + bv);
        }
    }
}

// ============ final GEMM (split-K z=16, atomic, bf16) ============
__global__ __launch_bounds__(256, 2) void gemm_fin(
    const ushort* A, const ushort* W, const float* bias, float* out, int K, int kchunk)
{
    __shared__ char smemf[32768];
    char* As = smemf;
    char* Ws = smemf + 16384;

    const int tid = threadIdx.x;
    const int lane = tid & 63, wv = tid >> 6, wr = wv >> 1, wc = wv & 1;
    const int lrow = lane & 15, lk = lane >> 4;
    const int n0 = blockIdx.y << 7;
    const int nkt = kchunk >> 6;
    const int ktbase = blockIdx.z * nkt;

    f32x4 acc[4][4];
    #pragma unroll
    for (int i = 0; i < 4; ++i)
        #pragma unroll
        for (int j = 0; j < 4; ++j) { f32x4 z = {0.f,0.f,0.f,0.f}; acc[i][j] = z; }

    const int srow = tid >> 3;
    const int g = (tid & 7) ^ (srow & 7);
    const ushort* pA = A + (size_t)srow * K + ktbase * 64 + g * 8;
    const ushort* pW = W + (size_t)(n0 + srow) * K + ktbase * 64 + g * 8;

    for (int t = 0; t < nkt; ++t) {
        #pragma unroll
        for (int j = 0; j < 4; ++j)
            gload16(pA + (size_t)j * 32 * K + (size_t)t * 64, As + j * 4096 + tid * 16);
        #pragma unroll
        for (int j = 0; j < 4; ++j)
            gload16(pW + (size_t)j * 32 * K + (size_t)t * 64, Ws + j * 4096 + tid * 16);
        __syncthreads();
        #pragma unroll
        for (int ks = 0; ks < 2; ++ks) {
            bf16x8 af[4], bfr[4];
            const int q = ks * 4 + lk;
            #pragma unroll
            for (int mi = 0; mi < 4; ++mi) {
                int row = wr * 64 + mi * 16 + lrow;
                af[mi] = *(const bf16x8*)(As + row * 128 + ((q ^ (row & 7)) << 4));
            }
            #pragma unroll
            for (int ni = 0; ni < 4; ++ni) {
                int row = wc * 64 + ni * 16 + lrow;
                bfr[ni] = *(const bf16x8*)(Ws + row * 128 + ((q ^ (row & 7)) << 4));
            }
            #pragma unroll
            for (int mi = 0; mi < 4; ++mi)
                #pragma unroll
                for (int ni = 0; ni < 4; ++ni)
                    acc[mi][ni] = __builtin_amdgcn_mfma_f32_16x16x32_bf16(af[mi], bfr[ni], acc[mi][ni], 0, 0, 0);
        }
        __syncthreads();
    }

    #pragma unroll
    for (int mi = 0; mi < 4; ++mi) {
        int mrow0 = wr * 64 + mi * 16 + lk * 4;
        #pragma unroll
        for (int ni = 0; ni < 4; ++ni) {
            int n = n0 + wc * 64 + ni * 16 + lrow;
            float bv = (blockIdx.z == 0) ? bias[n] : 0.f;
            #pragma unroll
            for (int r = 0; r < 4; ++r)
                atomicAdd(&out[(size_t)(mrow0 + r) * 1024 + n], acc[mi][ni][r] + bv);
        }
    }
}

// ---- fused softmax + context: y<2 = text d-halves, y>=2 = img branches (f32 feats) ----
__global__ void softmax_ctx(const float* __restrict__ tf,
                            const float* __restrict__ iof, const float* __restrict__ ipf,
                            const float* __restrict__ sc_to, const float* __restrict__ sc_tp,
                            const float* __restrict__ sc_io, const float* __restrict__ sc_ip,
                            const float* __restrict__ mask, ushort* __restrict__ combined)
{
    int b = blockIdx.x, y = blockIdx.y;
    int tid = threadIdx.x, lane = tid & 63, wv = tid >> 6;
    if (y >= 2) {
        int brn = y - 2;
        const float* A  = brn ? ipf : iof;
        const float* sc = brn ? sc_ip : sc_io;
        __shared__ float dist[64];
        if (tid < 64) {
            float s  = sc[b * 64 + tid];
            float mx = wredmax(s);
            float e  = __expf(s - mx);
            float sm = wredsum(e);
            dist[tid] = e / sm;
        }
        __syncthreads();
        int d0 = tid * 4;
        float a0 = 0, a1 = 0, a2 = 0, a3 = 0;
        const float* base = A + (size_t)b * 64 * 1024 + d0;
        #pragma unroll 4
        for (int n = 0; n < 64; ++n) {
            float w = dist[n];
            float4 t = *(const float4*)(base + (size_t)n * 1024);
            a0 += w * t.x; a1 += w * t.y; a2 += w * t.z; a3 += w * t.w;
        }
        uint2 o;
        o.x = pack_bf16x2(a0, a1);
        o.y = pack_bf16x2(a2, a3);
        *(uint2*)(combined + (size_t)b * 4096 + brn * 1024 + d0) = o;
    } else {
        __shared__ float d3[256], d4[256], red[8];
        float s3 = sc_to[b * 256 + tid], s4 = sc_tp[b * 256 + tid], m = mask[b * 256 + tid];
        float m3 = wredmax(s3), m4 = wredmax(s4);
        if (lane == 0) { red[wv] = m3; red[4 + wv] = m4; }
        __syncthreads();
        m3 = fmaxf(fmaxf(red[0], red[1]), fmaxf(red[2], red[3]));
        m4 = fmaxf(fmaxf(red[4], red[5]), fmaxf(red[6], red[7]));
        float e3 = __expf(s3 - m3) * m, e4 = __expf(s4 - m4) * m;
        float t3 = wredsum(e3), t4 = wredsum(e4);
        __syncthreads();
        if (lane == 0) { red[wv] = t3; red[4 + wv] = t4; }
        __syncthreads();
        t3 = red[0] + red[1] + red[2] + red[3];
        t4 = red[4] + red[5] + red[6] + red[7];
        d3[tid] = e3 / t3; d4[tid] = e4 / t4;
        __syncthreads();
        int d0 = y * 512 + tid * 2;
        float a0 = 0, a1 = 0, c0 = 0, c1 = 0;
        const float* base = tf + (size_t)b * 256 * 1024 + d0;
        #pragma unroll 4
        for (int l = 0; l < 256; ++l) {
            float w3 = d3[l], w4 = d4[l];
            float2 t = *(const float2*)(base + (size_t)l * 1024);
            a0 += w3 * t.x; a1 += w3 * t.y;
            c0 += w4 * t.x; c1 += w4 * t.y;
        }
        *(uint*)(combined + (size_t)b * 4096 + 2048 + d0) = pack_bf16x2(a0, a1);
        *(uint*)(combined + (size_t)b * 4096 + 3072 + d0) = pack_bf16x2(c0, c1);
    }
}

extern "C" void kernel_launch(void* const* d_in, const int* in_sizes, int n_in,
                              void* d_out, int out_size, void* d_ws, size_t ws_size,
                              hipStream_t stream) {
    const float* text_feat        = (const float*)d_in[0];
    const float* text_feats       = (const float*)d_in[1];
    const float* img_object_feat  = (const float*)d_in[2];
    const float* img_object_feats = (const float*)d_in[3];
    const float* img_place_feat   = (const float*)d_in[4];
    const float* img_place_feats  = (const float*)d_in[5];
    const float* src_mask         = (const float*)d_in[6];
    const float* v_to  = (const float*)d_in[7];
    const float* v_tp  = (const float*)d_in[8];
    const float* v_io  = (const float*)d_in[9];
    const float* v_ip  = (const float*)d_in[10];
    const float* W_t2o = (const float*)d_in[11];
    const float* W_t2p = (const float*)d_in[12];
    const float* W_o2t = (const float*)d_in[13];
    const float* W_p2t = (const float*)d_in[14];
    const float* W_oo  = (const float*)d_in[15];
    const float* b_oo  = (const float*)d_in[16];
    const float* W_pp  = (const float*)d_in[17];
    const float* b_pp  = (const float*)d_in[18];
    const float* W_tot = (const float*)d_in[19];
    const float* b_tot = (const float*)d_in[20];
    const float* W_tpt = (const float*)d_in[21];
    const float* b_tpt = (const float*)d_in[22];
    const float* W_out = (const float*)d_in[23];
    const float* b_out = (const float*)d_in[24];

    // ---- workspace layout ----
    char* p = (char*)d_ws;
    auto alloc = [&](size_t bytes) { char* r = p; p += (bytes + 255) & ~(size_t)255; return r; };
    ushort* wq_oo  = (ushort*)alloc((size_t)1024 * 1024 * 2);
    ushort* wq_pp  = (ushort*)alloc((size_t)1024 * 1024 * 2);
    ushort* wq_tot = (ushort*)alloc((size_t)1024 * 1024 * 2);
    ushort* wq_tpt = (ushort*)alloc((size_t)1024 * 1024 * 2);
    ushort* wb_out = (ushort*)alloc((size_t)1024 * 4096 * 2);
    ushort* tfq_bf  = (ushort*)alloc((size_t)128 * 1024 * 2);
    ushort* iofq_bf = (ushort*)alloc((size_t)128 * 1024 * 2);
    ushort* ipfq_bf = (ushort*)alloc((size_t)128 * 1024 * 2);
    uchar* w8_t2o = (uchar*)alloc((size_t)1024 * 1024);
    uchar* w8_t2p = (uchar*)alloc((size_t)1024 * 1024);
    uchar* w8_o2t = (uchar*)alloc((size_t)1024 * 1024);
    uchar* w8_p2t = (uchar*)alloc((size_t)1024 * 1024);
    uchar* tf8  = (uchar*)alloc((size_t)32768 * 1024);
    uchar* iof8 = (uchar*)alloc((size_t)8192 * 1024);
    uchar* ipf8 = (uchar*)alloc((size_t)8192 * 1024);
    // q buffers + scores CONTIGUOUS (single zero-fill range)
    float* q_tot = (float*)alloc((size_t)128 * 1024 * 4);
    float* q_tpt = (float*)alloc((size_t)128 * 1024 * 4);
    float* q_oo  = (float*)alloc((size_t)128 * 1024 * 4);
    float* q_pp  = (float*)alloc((size_t)128 * 1024 * 4);
    float* scores = (float*)alloc((size_t)(8192 * 2 + 32768 * 2) * 4);
    float* sc_io = scores, *sc_ip = scores + 8192, *sc_to = scores + 16384, *sc_tp = scores + 49152;
    ushort* comb_bf = (ushort*)alloc((size_t)128 * 4096 * 2);

    // ---- 1) fused conversions + zero-fill (q+scores, d_out) ----
    Cvt8Tab t8;
    const float* s8[7] = { W_t2o, W_t2p, W_o2t, W_p2t, text_feats, img_object_feats, img_place_feats };
    uchar* d8[7] = { w8_t2o, w8_t2p, w8_o2t, w8_p2t, tf8, iof8, ipf8 };
    unsigned n16[7] = { 65536, 65536, 65536, 65536, 2097152, 524288, 524288 };
    unsigned cum8 = 0;
    for (int i = 0; i < 7; ++i) { t8.src[i] = s8[i]; t8.dst[i] = d8[i]; t8.cum[i] = cum8; cum8 += n16[i]; }
    t8.src[7] = nullptr; t8.dst[7] = nullptr; t8.cum[7] = cum8; t8.cum[8] = cum8;

    CvtTab tb;
    const float* sb[8] = { W_oo, W_pp, W_tot, W_tpt, W_out, text_feat, img_object_feat, img_place_feat };
    ushort* db[8] = { wq_oo, wq_pp, wq_tot, wq_tpt, wb_out, tfq_bf, iofq_bf, ipfq_bf };
    unsigned nb4[8] = { 262144, 262144, 262144, 262144, 1048576, 32768, 32768, 32768 };
    unsigned cumb = 0;
    for (int i = 0; i < 8; ++i) { tb.src[i] = sb[i]; tb.dst[i] = db[i]; tb.cum[i] = cumb; cumb += nb4[i]; }
    tb.cum[8] = cumb;

    // zero ranges: q(4x512KB)+scores(320KB) = 2424832 B -> 151552 uint4; d_out 512KB -> 32768
    cvt_all<<<4096, 256, 0, stream>>>(t8, cum8, tb, cumb,
                                      (uint4*)q_tot, 151552u, (uint4*)d_out, 32768u);

    // ---- 2) fused q projections (bf16, split-K z=4) ----
    QArgs qa;
    qa.A[0] = tfq_bf;  qa.W[0] = wq_tot; qa.bias[0] = b_tot; qa.out[0] = q_tot;
    qa.A[1] = tfq_bf;  qa.W[1] = wq_tpt; qa.bias[1] = b_tpt; qa.out[1] = q_tpt;
    qa.A[2] = iofq_bf; qa.W[2] = wq_oo;  qa.bias[2] = b_oo;  qa.out[2] = q_oo;
    qa.A[3] = ipfq_bf; qa.W[3] = wq_pp;  qa.bias[3] = b_pp;  qa.out[3] = q_pp;
    gemm_q<<<dim3(4, 8, 4), 256, 0, stream>>>(qa, 256);

    // ---- 3) merged score GEMMs (fp8 packed-pair, 128x256 tile, 2560 blocks) ----
    PArgs pi;
    pi.A[0] = iof8;   pi.Wa[0] = w8_o2t; pi.Wb[0] = w8_o2t;
    pi.qa[0] = q_tot; pi.qb[0] = q_tot;  pi.va[0] = v_to; pi.vb[0] = v_to;
    pi.oa[0] = sc_io; pi.ob[0] = sc_io;
    pi.A[1] = ipf8;   pi.Wa[1] = w8_p2t; pi.Wb[1] = w8_p2t;
    pi.qa[1] = q_tpt; pi.qb[1] = q_tpt;  pi.va[1] = v_tp; pi.vb[1] = v_tp;
    pi.oa[1] = sc_ip; pi.ob[1] = sc_ip;

    PArgs pt;
    pt.A[0] = tf8;    pt.Wa[0] = w8_t2o; pt.Wb[0] = w8_t2p;
    pt.qa[0] = q_oo;  pt.qb[0] = q_pp;   pt.va[0] = v_io; pt.vb[0] = v_ip;
    pt.oa[0] = sc_to; pt.ob[0] = sc_tp;
    pt.A[1] = pt.A[0]; pt.Wa[1] = pt.Wa[0]; pt.Wb[1] = pt.Wb[0];
    pt.qa[1] = pt.qa[0]; pt.qb[1] = pt.qb[0]; pt.va[1] = pt.va[0]; pt.vb[1] = pt.vb[0];
    pt.oa[1] = pt.oa[0]; pt.ob[1] = pt.ob[0];

    gemm_pipe8<<<dim3(2560), 256, 49152, stream>>>(pi, pt);

    // ---- 4) fused softmax + context -> combined (bf16) ----
    softmax_ctx<<<dim3(128, 4), 256, 0, stream>>>(
        text_feats, img_object_feats, img_place_feats,
        sc_to, sc_tp, sc_io, sc_ip, src_mask, comb_bf);

    // ---- 5) out = combined @ W_out^T + b_out (split-K=16, atomic) ----
    gemm_fin<<<dim3(1, 8, 16), 256, 0, stream>>>(comb_bf, wb_out, b_out, (float*)d_out, 4096, 256);
}